// Round 6
// baseline (991.930 us; speedup 1.0000x reference)
//
#include <hip/hip_runtime.h>
#include <cstdint>
#include <cstddef>

// ---------------------------------------------------------------------------
// Fine_Grain_Layer. f32 I/O, bf16 MFMA operands, f32 accumulate.
// R13 -> R14: R13 (transposed coef MLP) = 765.5us total, edge now faster
// than the 162us harness poison fill (out of top-5), no spill -> the
// operand-swap + in-lane-LN pattern is proven register-safe; R12's spill
// was the persistent-grid loop structure, not the transposed epilogues.
// R14 applies the SAME pattern to LN1 and LN2 (grid/loop/prefetch
// unchanged from R13): MFMA16(W, inp, acc) -> lane holds 16 features of
// edge l15; LN stats = 16 in-lane adds + 2 shfl_xor(16/32) (was 32
// shuffles); gamma/beta/bias = floatx4 LDS broadcasts; msgb writes = 4x
// ds_write_b64 (2-way bank aliasing = free); acc updated in place (no
// vv/vm side arrays, ~-16 peak regs per LN). a2/m0/m1 reads and the
// global msgbuf store are byte-identical to R13 (block (2t+gh)^x7 <->
// read (b^x7) verified). ~-56 shuffles, -24 LDS ops, -80 VALU per iter.
// Spill tripwire: FETCH must stay ~44.5 MB, WRITE ~86 MB.
// ~162 us of dur is the harness's 1 GiB ws poison fill (uncontrollable).
// ---------------------------------------------------------------------------

typedef short bf16x8 __attribute__((ext_vector_type(8)));
typedef float floatx4 __attribute__((ext_vector_type(4)));

#define MFMA16(a, b, c) __builtin_amdgcn_mfma_f32_16x16x32_bf16((a), (b), (c), 0, 0, 0)

__device__ __forceinline__ unsigned short f2bf(float f) {
    unsigned int u = __builtin_bit_cast(unsigned int, f);
    u += 0x7fffu + ((u >> 16) & 1u);   // round to nearest even
    return (unsigned short)(u >> 16);
}
__device__ __forceinline__ float bf2f(unsigned short u) {
    unsigned int x = ((unsigned int)u) << 16;
    return __builtin_bit_cast(float, x);
}
__device__ __forceinline__ bf16x8 cvt8(const float* __restrict__ p) {
    bf16x8 r;
    #pragma unroll
    for (int j = 0; j < 8; j++) r[j] = (short)f2bf(p[j]);
    return r;
}
__device__ __forceinline__ float rowsum16(float x) {
    x += __shfl_xor(x, 1);
    x += __shfl_xor(x, 2);
    x += __shfl_xor(x, 4);
    x += __shfl_xor(x, 8);
    return x;
}
__device__ __forceinline__ float rowmax16(float x) {
    x = fmaxf(x, __shfl_xor(x, 1));
    x = fmaxf(x, __shfl_xor(x, 2));
    x = fmaxf(x, __shfl_xor(x, 4));
    x = fmaxf(x, __shfl_xor(x, 8));
    return x;
}
__device__ __forceinline__ float lrelu(float x) { return x > 0.f ? x : 0.01f * x; }
__device__ __forceinline__ float ln_rstd(float s2, float mean) {
    float var = s2 * 0.015625f - mean * mean;
    return rsqrtf(fmaxf(var, 0.0f) + 1e-5f);
}

__constant__ float INVSIG[16] = {
    1.0f, 0.6666666865f, 0.4444444597f, 0.2962962985f, 0.1975308657f,
    0.1316872428f, 0.0877914950f, 0.0585276633f, 0.0390184447f, 0.0260122959f,
    0.0173415299f, 0.0115610203f, 0.0077073467f, 0.0051382311f, 0.0034254875f, 0.0f};

// ---------------------------------------------------------------------------
// Pre-convert h (2x524288) and ef (2x8388608) to bf16. Quad-granular.
__global__ void prep_kernel(const float* __restrict__ hA, const float* __restrict__ hB,
                            const float* __restrict__ efA, const float* __restrict__ efB,
                            unsigned short* __restrict__ hbA, unsigned short* __restrict__ hbB,
                            unsigned short* __restrict__ efbA, unsigned short* __restrict__ efbB)
{
    int q = blockIdx.x * 256 + threadIdx.x;   // 4,456,448 quads exactly
    const float* s; unsigned short* d; int off;
    if (q < 131072)        { s = hA;  d = hbA;  off = q; }
    else if (q < 262144)   { s = hB;  d = hbB;  off = q - 131072; }
    else if (q < 2359296)  { s = efA; d = efbA; off = q - 262144; }
    else                   { s = efB; d = efbB; off = q - 2359296; }
    float4 v = *(const float4*)(s + (size_t)off * 4);
    ushort4 o;
    o.x = f2bf(v.x); o.y = f2bf(v.y); o.z = f2bf(v.z); o.w = f2bf(v.w);
    *(ushort4*)(d + (size_t)off * 4) = o;
}

// ---------------------------------------------------------------------------
__global__ void hist_kernel(const int* __restrict__ dstA, const int* __restrict__ dstB,
                            int* __restrict__ histA, int* __restrict__ histB)
{
    int e = blockIdx.x * 256 + threadIdx.x;   // exactly 262144
    atomicAdd(&histA[dstA[e]], 1);
    atomicAdd(&histB[dstB[e]], 1);
}

__global__ void scan_kernel(const int* __restrict__ histA, const int* __restrict__ histB,
                            int* __restrict__ rowptrA, int* __restrict__ rowptrB)
{
    const int b = blockIdx.x;   // 0 = A, 1 = B
    const int* hist = b ? histB : histA;
    int* rowptr = b ? rowptrB : rowptrA;
    __shared__ int part[1024];
    int t = threadIdx.x;
    int v[8]; int s = 0;
    #pragma unroll
    for (int j = 0; j < 8; j++) { v[j] = hist[t * 8 + j]; s += v[j]; }
    part[t] = s;
    __syncthreads();
    for (int off = 1; off < 1024; off <<= 1) {
        int x = part[t];
        int y = (t >= off) ? part[t - off] : 0;
        __syncthreads();
        part[t] = x + y;
        __syncthreads();
    }
    int run = (t > 0) ? part[t - 1] : 0;
    #pragma unroll
    for (int j = 0; j < 8; j++) { rowptr[t * 8 + j] = run; run += v[j]; }
    if (t == 1023) rowptr[8192] = run;
}

// pos[e] = slot of edge e in dst-CSR order
__global__ void scatter_kernel(const int* __restrict__ dstA, const int* __restrict__ dstB,
                               const int* __restrict__ rowptrA, const int* __restrict__ rowptrB,
                               int* __restrict__ curA, int* __restrict__ curB,
                               int* __restrict__ posA, int* __restrict__ posB)
{
    int e = blockIdx.x * 256 + threadIdx.x;   // exactly 262144
    int dA = dstA[e];
    posA[e] = rowptrA[dA] + atomicAdd(&curA[dA], 1);
    int dB = dstB[e];
    posB[e] = rowptrB[dB] + atomicAdd(&curB[dB], 1);
}

// ---------------------------------------------------------------------------
// Edge kernel, both branches: one wave = 16 edges; 8 waves/block; barrier-free
// body; fully transposed-C MFMA (lane = edge l15, regs = features).
// Minimal prefetch: next iter's idx (3 ints) + ef (1 bf16x8) only.
__global__ __launch_bounds__(512, 2) void edge_kernel(
    const float* __restrict__ coordsA, const unsigned short* __restrict__ hbA,
    const unsigned short* __restrict__ efbA, const int* __restrict__ srcA,
    const int* __restrict__ dstA, const int* __restrict__ posA,
    const float* __restrict__ coordsB, const unsigned short* __restrict__ hbB,
    const unsigned short* __restrict__ efbB, const int* __restrict__ srcB,
    const int* __restrict__ dstB, const int* __restrict__ posB,
    const float* __restrict__ eW1, const float* __restrict__ eb1,
    const float* __restrict__ eg1, const float* __restrict__ ebt1,
    const float* __restrict__ eW2, const float* __restrict__ eb2,
    const float* __restrict__ eg2, const float* __restrict__ ebt2,
    const float* __restrict__ cW1, const float* __restrict__ cb1,
    const float* __restrict__ cg1, const float* __restrict__ cbt1,
    const float* __restrict__ cW2, const float* __restrict__ cb2,
    unsigned short* __restrict__ msgbufA, unsigned short* __restrict__ msgbufB,
    float* __restrict__ xupA, float* __restrict__ xupB)
{
    // XOR-swizzled LDS tiles: addr = row*stride + ((blk ^ (row&7))<<3) + (col&7)
    __shared__ __attribute__((aligned(16))) short Wt1[64 * 192];   // 24576 B
    __shared__ __attribute__((aligned(16))) short Wt2s[64 * 64];   //  8192 B
    __shared__ __attribute__((aligned(16))) short Wc1s[64 * 64];   //  8192 B
    __shared__ __attribute__((aligned(16))) float pb[644];         //  2576 B
    __shared__ __attribute__((aligned(16))) short msgb[8][16 * 64];// 16384 B -> 59920 total

    const int tid = threadIdx.x;

    for (int i = tid; i < 64 * 192; i += 512) {
        int n = i / 192, kk = i - n * 192;
        float w = (kk < 175) ? eW1[kk * 64 + n] : 0.0f;
        Wt1[n * 192 + ((((kk >> 3) ^ (n & 7)) << 3) | (kk & 7))] = (short)f2bf(w);
    }
    for (int i = tid; i < 4096; i += 512) {
        int n = i >> 6, kk = i & 63;
        int o = n * 64 + ((((kk >> 3) ^ (n & 7)) << 3) | (kk & 7));
        Wt2s[o] = (short)f2bf(eW2[kk * 64 + n]);
        Wc1s[o] = (short)f2bf(cW1[kk * 64 + n]);
    }
    if (tid < 64) {
        pb[tid]       = eb1[tid];
        pb[64 + tid]  = eg1[tid];
        pb[128 + tid] = ebt1[tid];
        pb[192 + tid] = eb2[tid];
        pb[256 + tid] = eg2[tid];
        pb[320 + tid] = ebt2[tid];
        pb[384 + tid] = cb1[tid];
        pb[448 + tid] = cg1[tid];
        pb[512 + tid] = cbt1[tid];
        pb[576 + tid] = cW2[tid];
    }
    if (tid == 0) pb[640] = cb2[0];
    __syncthreads();   // the ONLY barrier

    const int wave = tid >> 6;
    const int lane = tid & 63;
    const int l15 = lane & 15;
    const int g = lane >> 4;
    const int x7 = l15 & 7;
    const int g2 = 4 * (g & 1);          // b64 sub-block offset (shorts)
    const int gh = g >> 1;               // feature block half
    const int gi0 = blockIdx.x * 8 + wave;   // < 8192

    // iteration it (0..3): branch = it>>1; in-branch edge base alternates
    // between eA0 (it 0,2) and eA1 (it 1,3).
    const int eA0 = (gi0 & 16383) * 16 + l15;
    const int eA1 = eA0 + 8192 * 16;

    // prefetch it=0 (branch A, edge eA0)
    int s_n  = srcA[eA0];
    int d_n  = dstA[eA0];
    int sl_n = posA[eA0];
    bf16x8 ef_n = *(const bf16x8*)(efbA + (size_t)eA0 * 32 + 8 * g);

    #pragma unroll 1
    for (int it = 0; it < 4; ++it) {
        const int br = it >> 1;
        const float* coords = br ? coordsB : coordsA;
        const unsigned short* hb = br ? hbB : hbA;
        unsigned short* msgbuf = br ? msgbufB : msgbufA;
        float* xup = br ? xupB : xupA;

        const int s = s_n, d0 = d_n, slot = sl_n;
        const bf16x8 ef = ef_n;

        // current-iteration dependent loads: issue ASAP
        bf16x8 h0 = *(const bf16x8*)(hb + (size_t)s * 64 + 8 * g);
        bf16x8 h1 = *(const bf16x8*)(hb + (size_t)s * 64 + 32 + 8 * g);
        bf16x8 h2 = *(const bf16x8*)(hb + (size_t)d0 * 64 + 8 * g);
        bf16x8 h3 = *(const bf16x8*)(hb + (size_t)d0 * 64 + 32 + 8 * g);
        float cs0 = coords[s * 3 + 0];
        float cs1 = coords[s * 3 + 1];
        float cs2 = coords[s * 3 + 2];
        float cd0 = coords[d0 * 3 + 0];
        float cd1 = coords[d0 * 3 + 1];
        float cd2 = coords[d0 * 3 + 2];

        // prefetch next iteration's idx + ef (addresses independent of above)
        if (it < 3) {
            const int brn = (it + 1) >> 1;
            const int en = (it & 1) ? eA0 : eA1;
            const int* srcN = brn ? srcB : srcA;
            const int* dstN = brn ? dstB : dstA;
            const int* posN = brn ? posB : posA;
            const unsigned short* efbN = brn ? efbB : efbA;
            s_n  = srcN[en];
            d_n  = dstN[en];
            sl_n = posN[en];
            ef_n = *(const bf16x8*)(efbN + (size_t)en * 32 + 8 * g);
        }

        const float xr0 = cs0 - cd0;
        const float xr1 = cs1 - cd1;
        const float xr2 = cs2 - cd2;
        const float d2 = xr0 * xr0 + xr1 * xr1 + xr2 * xr2;

        bf16x8 af5;
        #pragma unroll
        for (int j = 0; j < 8; j++) {
            int idx = 8 * g + j;
            float rv = 0.0f;
            if (g < 2 && idx < 15) rv = __expf(-d2 * INVSIG[idx & 15]);
            af5[j] = (short)f2bf(rv);
        }

        // layer 1 (transposed): acc1[t][r] = out[feature 16t+4g+r][edge l15]
        floatx4 acc1[4];
        #pragma unroll
        for (int t = 0; t < 4; t++) acc1[t] = (floatx4)0.0f;
        {
            bf16x8 af[6] = {h0, h1, h2, h3, ef, af5};
            #pragma unroll
            for (int c = 0; c < 6; c++) {
                #pragma unroll
                for (int t = 0; t < 4; t++) {
                    bf16x8 b = *(const bf16x8*)(&Wt1[(t * 16 + l15) * 192 + ((((c << 2) | g) ^ x7) << 3)]);
                    acc1[t] = MFMA16(b, af[c], acc1[t]);   // W as A, inp as B -> C^T
                }
            }
        }

        // LN1 (per-edge, in-lane stats + 2 shuffles); lrelu; b64 writes
        {
            float s1 = 0.f, s2 = 0.f;
            #pragma unroll
            for (int t = 0; t < 4; t++) {
                const floatx4 bv = *(const floatx4*)&pb[t * 16 + 4 * g];
                #pragma unroll
                for (int r = 0; r < 4; r++) {
                    float x = acc1[t][r] + bv[r];
                    acc1[t][r] = x;
                    s1 += x; s2 += x * x;
                }
            }
            s1 += __shfl_xor(s1, 16); s1 += __shfl_xor(s1, 32);
            s2 += __shfl_xor(s2, 16); s2 += __shfl_xor(s2, 32);
            const float mean = s1 * 0.015625f;
            const float rstd = ln_rstd(s2, mean);
            #pragma unroll
            for (int t = 0; t < 4; t++) {
                const floatx4 gv = *(const floatx4*)&pb[64 + t * 16 + 4 * g];
                const floatx4 bt = *(const floatx4*)&pb[128 + t * 16 + 4 * g];
                float x0 = lrelu((acc1[t][0] - mean) * rstd * gv[0] + bt[0]);
                float x1 = lrelu((acc1[t][1] - mean) * rstd * gv[1] + bt[1]);
                float x2 = lrelu((acc1[t][2] - mean) * rstd * gv[2] + bt[2]);
                float x3 = lrelu((acc1[t][3] - mean) * rstd * gv[3] + bt[3]);
                uint2 pk;
                pk.x = (unsigned int)f2bf(x0) | ((unsigned int)f2bf(x1) << 16);
                pk.y = (unsigned int)f2bf(x2) | ((unsigned int)f2bf(x3) << 16);
                const int blk = (2 * t + gh) ^ x7;
                *(uint2*)&msgb[wave][l15 * 64 + (blk << 3) + g2] = pk;
            }
        }

        // layer 2 (transposed): same reads as before (operand role swapped)
        bf16x8 a2[2];
        a2[0] = *(const bf16x8*)(&msgb[wave][l15 * 64 + (((g) ^ x7) << 3)]);
        a2[1] = *(const bf16x8*)(&msgb[wave][l15 * 64 + (((4 | g) ^ x7) << 3)]);
        floatx4 acc2[4];
        #pragma unroll
        for (int t = 0; t < 4; t++) acc2[t] = (floatx4)0.0f;
        #pragma unroll
        for (int c = 0; c < 2; c++) {
            #pragma unroll
            for (int t = 0; t < 4; t++) {
                bf16x8 b = *(const bf16x8*)(&Wt2s[(t * 16 + l15) * 64 + ((((c << 2) | g) ^ x7) << 3)]);
                acc2[t] = MFMA16(b, a2[c], acc2[t]);
            }
        }
        // LN2 (no lrelu), b64 writes of final msg back to msgb
        {
            float s1 = 0.f, s2 = 0.f;
            #pragma unroll
            for (int t = 0; t < 4; t++) {
                const floatx4 bv = *(const floatx4*)&pb[192 + t * 16 + 4 * g];
                #pragma unroll
                for (int r = 0; r < 4; r++) {
                    float x = acc2[t][r] + bv[r];
                    acc2[t][r] = x;
                    s1 += x; s2 += x * x;
                }
            }
            s1 += __shfl_xor(s1, 16); s1 += __shfl_xor(s1, 32);
            s2 += __shfl_xor(s2, 16); s2 += __shfl_xor(s2, 32);
            const float mean = s1 * 0.015625f;
            const float rstd = ln_rstd(s2, mean);
            #pragma unroll
            for (int t = 0; t < 4; t++) {
                const floatx4 gv = *(const floatx4*)&pb[256 + t * 16 + 4 * g];
                const floatx4 bt = *(const floatx4*)&pb[320 + t * 16 + 4 * g];
                float x0 = (acc2[t][0] - mean) * rstd * gv[0] + bt[0];
                float x1 = (acc2[t][1] - mean) * rstd * gv[1] + bt[1];
                float x2 = (acc2[t][2] - mean) * rstd * gv[2] + bt[2];
                float x3 = (acc2[t][3] - mean) * rstd * gv[3] + bt[3];
                uint2 pk;
                pk.x = (unsigned int)f2bf(x0) | ((unsigned int)f2bf(x1) << 16);
                pk.y = (unsigned int)f2bf(x2) | ((unsigned int)f2bf(x3) << 16);
                const int blk = (2 * t + gh) ^ x7;
                *(uint2*)&msgb[wave][l15 * 64 + (blk << 3) + g2] = pk;
            }
        }

        // single re-read of final msg fragments: reused for the global store
        // AND as the coef-MLP B-operand (transposed MFMA).
        bf16x8 m0 = *(const bf16x8*)(&msgb[wave][l15 * 64 + (((g) ^ x7) << 3)]);
        bf16x8 m1 = *(const bf16x8*)(&msgb[wave][l15 * 64 + (((4 | g) ^ x7) << 3)]);
        {
            unsigned short* mrow = msgbuf + (size_t)slot * 64;
            *(bf16x8*)(mrow + 8 * g)      = m0;
            *(bf16x8*)(mrow + 32 + 8 * g) = m1;
        }

        // coef MLP, TRANSPOSED-C: W-frag as A-operand, msg-frag as B-operand.
        // acc3[t][r] = coef-layer feature (16t+4g+r) of edge l15.
        floatx4 acc3[4];
        #pragma unroll
        for (int t = 0; t < 4; t++) acc3[t] = (floatx4)0.0f;
        #pragma unroll
        for (int c = 0; c < 2; c++) {
            #pragma unroll
            for (int t = 0; t < 4; t++) {
                bf16x8 b = *(const bf16x8*)(&Wc1s[(t * 16 + l15) * 64 + ((((c << 2) | g) ^ x7) << 3)]);
                acc3[t] = MFMA16(b, c == 0 ? m0 : m1, acc3[t]);
            }
        }
        float cf;
        {
            float s1 = 0.f, s2 = 0.f;
            #pragma unroll
            for (int t = 0; t < 4; t++) {
                const floatx4 bv = *(const floatx4*)&pb[384 + t * 16 + 4 * g];
                #pragma unroll
                for (int r = 0; r < 4; r++) {
                    float x = acc3[t][r] + bv[r];
                    acc3[t][r] = x;
                    s1 += x; s2 += x * x;
                }
            }
            s1 += __shfl_xor(s1, 16); s1 += __shfl_xor(s1, 32);
            s2 += __shfl_xor(s2, 16); s2 += __shfl_xor(s2, 32);
            const float mean = s1 * 0.015625f;
            const float rstd = ln_rstd(s2, mean);
            float p = 0.f;
            #pragma unroll
            for (int t = 0; t < 4; t++) {
                const floatx4 gv = *(const floatx4*)&pb[448 + t * 16 + 4 * g];
                const floatx4 bt = *(const floatx4*)&pb[512 + t * 16 + 4 * g];
                const floatx4 wv = *(const floatx4*)&pb[576 + t * 16 + 4 * g];
                #pragma unroll
                for (int r = 0; r < 4; r++) {
                    float x = (acc3[t][r] - mean) * rstd * gv[r] + bt[r];
                    p += lrelu(x) * wv[r];
                }
            }
            p += __shfl_xor(p, 16); p += __shfl_xor(p, 32);
            cf = p + pb[640];       // every lane: coef of its edge l15
        }

        if (g < 3) {
            float xrg = (g == 0) ? xr0 : (g == 1) ? xr1 : xr2;
            atomicAdd(&xup[(size_t)d0 * 3 + g], xrg * cf);
        }
    }
}

// ---------------------------------------------------------------------------
// Gather-reduce over CSR-ordered msgbuf: contiguous streaming reads.
__global__ __launch_bounds__(256, 4) void gather_kernel(
    const int* __restrict__ rowptrA, const int* __restrict__ rowptrB,
    const unsigned short* __restrict__ msgbufA, const unsigned short* __restrict__ msgbufB,
    float* __restrict__ aggrA, float* __restrict__ aggrB)
{
    const int tid = threadIdx.x;
    const int wave = tid >> 6, lane = tid & 63;
    const int nwaves = gridDim.x * 4;
    for (int u = blockIdx.x * 4 + wave; u < 16384; u += nwaves) {
        const int br = u >> 13;
        const int n = u & 8191;
        const int* rowptr = br ? rowptrB : rowptrA;
        const unsigned short* mb = br ? msgbufB : msgbufA;
        float* aggr = br ? aggrB : aggrA;
        int base = rowptr[n];
        int deg = rowptr[n + 1] - base;
        float a[8];
        #pragma unroll
        for (int j = 0; j < 8; j++) a[j] = 0.f;
        int i = 0;
        for (; i + 8 <= deg; i += 8) {
            #pragma unroll
            for (int j = 0; j < 8; j++)
                a[j] += bf2f(mb[(size_t)(base + i + j) * 64 + lane]);
        }
        for (; i < deg; i++) a[0] += bf2f(mb[(size_t)(base + i) * 64 + lane]);
        float t = (a[0] + a[1]) + (a[2] + a[3]) + ((a[4] + a[5]) + (a[6] + a[7]));
        aggr[(size_t)n * 64 + lane] = t / fmaxf((float)deg, 1.0f);
    }
}

// ---------------------------------------------------------------------------
__global__ __launch_bounds__(256, 2) void qkv_kernel(
    const unsigned short* __restrict__ hbA, const unsigned short* __restrict__ hbB,
    const float* __restrict__ qW, const float* __restrict__ kW,
    const float* __restrict__ vW,
    unsigned short* __restrict__ qo, unsigned short* __restrict__ ko,
    unsigned short* __restrict__ vTo)
{
    __shared__ __attribute__((aligned(16))) short Wq[64 * 64];
    __shared__ __attribute__((aligned(16))) short Wk[64 * 64];
    __shared__ __attribute__((aligned(16))) short Wv[64 * 64];
    const int tid = threadIdx.x;
    for (int i = tid; i < 4096; i += 256) {
        int n = i >> 6, kk = i & 63;
        int o = n * 64 + ((((kk >> 3) ^ (n & 7)) << 3) | (kk & 7));
        Wq[o] = (short)f2bf(qW[kk * 64 + n]);
        Wk[o] = (short)f2bf(kW[kk * 64 + n]);
        Wv[o] = (short)f2bf(vW[kk * 64 + n]);
    }
    __syncthreads();
    const int wave = tid >> 6, lane = tid & 63, l15 = lane & 15, g = lane >> 4;
    const int x7 = l15 & 7;
    const int row0 = blockIdx.x * 64 + wave * 16;
    bf16x8 aA[2], aB[2];
    aA[0] = *(const bf16x8*)(hbA + (size_t)(row0 + l15) * 64 + 8 * g);
    aA[1] = *(const bf16x8*)(hbA + (size_t)(row0 + l15) * 64 + 32 + 8 * g);
    aB[0] = *(const bf16x8*)(hbB + (size_t)(row0 + l15) * 64 + 8 * g);
    aB[1] = *(const bf16x8*)(hbB + (size_t)(row0 + l15) * 64 + 32 + 8 * g);
    floatx4 aq[4], ak4[4], av[4];
    #pragma unroll
    for (int t = 0; t < 4; t++) { aq[t] = (floatx4)0.0f; ak4[t] = (floatx4)0.0f; av[t] = (floatx4)0.0f; }
    #pragma unroll
    for (int c = 0; c < 2; c++) {
        #pragma unroll
        for (int t = 0; t < 4; t++) {
            int wo = (t * 16 + l15) * 64 + ((((c << 2) | g) ^ x7) << 3);
            aq[t] = MFMA16(aA[c], *(const bf16x8*)(&Wq[wo]), aq[t]);
            ak4[t] = MFMA16(aB[c], *(const bf16x8*)(&Wk[wo]), ak4[t]);
            av[t] = MFMA16(aB[c], *(const bf16x8*)(&Wv[wo]), av[t]);
        }
    }
    #pragma unroll
    for (int t = 0; t < 4; t++) {
        #pragma unroll
        for (int r = 0; r < 4; r++) {
            int orow = row0 + 4 * g + r, ocol = t * 16 + l15;
            qo[(size_t)orow * 64 + ocol] = f2bf(lrelu(aq[t][r]));
            ko[(size_t)orow * 64 + ocol] = f2bf(lrelu(ak4[t][r]));
            vTo[(size_t)ocol * 8192 + orow] = f2bf(av[t][r]);   // v transposed
        }
    }
}

// ---------------------------------------------------------------------------
// Flash attention, K-split=8, direct L2 b-frag loads, no barriers.
__global__ __launch_bounds__(256, 4) void attn_kernel(
    const unsigned short* __restrict__ qb_, const unsigned short* __restrict__ kb_,
    const unsigned short* __restrict__ vT,
    float* __restrict__ Opart, float* __restrict__ ml)
{
    __shared__ __attribute__((aligned(16))) short pbuf[4][16 * 64];
    const int tid = threadIdx.x;
    const int wave = tid >> 6, lane = tid & 63, l15 = lane & 15, g = lane >> 4;
    const int x7 = l15 & 7;
    const int qblock = blockIdx.x >> 3;         // 128 q-blocks
    const int split = blockIdx.x & 7;           // 8 k-splits
    const int qrow0 = qblock * 64 + wave * 16;
    const int kbase = split * 1024;
    bf16x8 qf[2];
    qf[0] = *(const bf16x8*)(qb_ + (size_t)(qrow0 + l15) * 64 + 8 * g);
    qf[1] = *(const bf16x8*)(qb_ + (size_t)(qrow0 + l15) * 64 + 32 + 8 * g);
    float m_[4], l_[4];
    floatx4 oacc[4];
    #pragma unroll
    for (int r = 0; r < 4; r++) { m_[r] = -1.0e30f; l_[r] = 0.f; }
    #pragma unroll
    for (int t = 0; t < 4; t++) oacc[t] = (floatx4)0.0f;

    for (int kt = 0; kt < 16; kt++) {
        const int krow0 = kbase + kt * 64;
        floatx4 sacc[4];
        #pragma unroll
        for (int t = 0; t < 4; t++) sacc[t] = (floatx4)0.0f;
        #pragma unroll
        for (int c = 0; c < 2; c++) {
            #pragma unroll
            for (int t = 0; t < 4; t++) {
                bf16x8 b = *(const bf16x8*)(kb_ + (size_t)(krow0 + t * 16 + l15) * 64 + 32 * c + 8 * g);
                sacc[t] = MFMA16(qf[c], b, sacc[t]);
            }
        }
        #pragma unroll
        for (int r = 0; r < 4; r++) {
            float mx = fmaxf(fmaxf(sacc[0][r], sacc[1][r]), fmaxf(sacc[2][r], sacc[3][r]));
            mx = rowmax16(mx);
            float mn = fmaxf(m_[r], mx);
            float sc = __expf(fminf(m_[r] - mn, 0.f));
            float ps = 0.f;
            int row = 4 * g + r;
            int rbase = row * 64;
            int r7 = row & 7;
            #pragma unroll
            for (int t = 0; t < 4; t++) {
                float p = __expf(fminf(sacc[t][r] - mn, 0.f));
                ps += p;
                pbuf[wave][rbase + (((((t << 1) | (l15 >> 3)) ^ r7) << 3) | x7)] = (short)f2bf(p);
            }
            ps = rowsum16(ps);
            l_[r] = l_[r] * sc + ps;
            m_[r] = mn;
            #pragma unroll
            for (int t = 0; t < 4; t++) oacc[t][r] *= sc;
        }
        bf16x8 pf[2];
        pf[0] = *(const bf16x8*)(&pbuf[wave][l15 * 64 + (((g) ^ x7) << 3)]);
        pf[1] = *(const bf16x8*)(&pbuf[wave][l15 * 64 + (((4 | g) ^ x7) << 3)]);
        #pragma unroll
        for (int c = 0; c < 2; c++) {
            #pragma unroll
            for (int t = 0; t < 4; t++) {
                bf16x8 b = *(const bf16x8*)(vT + (size_t)(t * 16 + l15) * 8192 + krow0 + 32 * c + 8 * g);
                oacc[t] = MFMA16(pf[c], b, oacc[t]);
            }
        }
    }
    #pragma unroll
    for (int t = 0; t < 4; t++) {
        #pragma unroll
        for (int r = 0; r < 4; r++) {
            int row = qrow0 + 4 * g + r;
            Opart[((size_t)split * 8192 + row) * 64 + t * 16 + l15] = oacc[t][r];
        }
    }
    if (l15 == 0) {
        #pragma unroll
        for (int r = 0; r < 4; r++) {
            int row = qrow0 + 4 * g + r;
            ml[((size_t)split * 8192 + row) * 2 + 0] = m_[r];
            ml[((size_t)split * 8192 + row) * 2 + 1] = l_[r];
        }
    }
}

__global__ void combine_kernel(const float* __restrict__ Opart, const float* __restrict__ ml,
                               unsigned short* __restrict__ attb)
{
    int idx = blockIdx.x * 256 + threadIdx.x;   // 8192*64
    int row = idx >> 6, col = idx & 63;
    float mm = -1.0e30f;
    #pragma unroll
    for (int s = 0; s < 8; s++) mm = fmaxf(mm, ml[((size_t)s * 8192 + row) * 2]);
    float l = 0.f, o = 0.f;
    #pragma unroll
    for (int s = 0; s < 8; s++) {
        float w = __expf(ml[((size_t)s * 8192 + row) * 2] - mm);
        l += w * ml[((size_t)s * 8192 + row) * 2 + 1];
        o += w * Opart[((size_t)s * 8192 + row) * 64 + col];
    }
    attb[(size_t)row * 64 + col] = f2bf(o / l);
}

// ---------------------------------------------------------------------------
__global__ __launch_bounds__(256, 2) void node_kernel(
    const float* __restrict__ hA, const float* __restrict__ hB,
    const float* __restrict__ origA, const float* __restrict__ origB,
    const unsigned short* __restrict__ attb,
    const float* __restrict__ aggrA, const float* __restrict__ aggrB,
    const float* __restrict__ nW1, const float* __restrict__ nb1,
    const float* __restrict__ ng1, const float* __restrict__ nbt1,
    const float* __restrict__ nW2, const float* __restrict__ nb2,
    const float* __restrict__ ng2, const float* __restrict__ nbt2,
    float* __restrict__ out)
{
    __shared__ __attribute__((aligned(16))) short W1t[64 * 256];
    __shared__ __attribute__((aligned(16))) short W2t[64 * 64];
    __shared__ __attribute__((aligned(16))) float pb[6 * 64];
    __shared__ __attribute__((aligned(16))) short ubuf[4][16 * 64];
    const int tid = threadIdx.x;
    for (int i = tid; i < 64 * 256; i += 256) {
        int n = i >> 8, kk = i & 255;
        W1t[n * 256 + ((((kk >> 3) ^ (n & 7)) << 3) | (kk & 7))] = (short)f2bf(nW1[kk * 64 + n]);
    }
    for (int i = tid; i < 4096; i += 256) {
        int n = i >> 6, kk = i & 63;
        W2t[n * 64 + ((((kk >> 3) ^ (n & 7)) << 3) | (kk & 7))] = (short)f2bf(nW2[kk * 64 + n]);
    }
    if (tid < 64) {
        pb[tid]       = nb1[tid];
        pb[64 + tid]  = ng1[tid];
        pb[128 + tid] = nbt1[tid];
        pb[192 + tid] = nb2[tid];
        pb[256 + tid] = ng2[tid];
        pb[320 + tid] = nbt2[tid];
    }
    __syncthreads();   // only barrier
    const int wave = tid >> 6, lane = tid & 63, l15 = lane & 15, g = lane >> 4;
    const int x7 = l15 & 7;
    const int unit = blockIdx.x * 4 + wave;          // 1024 units
    const int br = unit >> 9;
    const int nb_ = (unit & 511) * 16;
    const float* h = br ? hB : hA;
    const float* orig = br ? origB : origA;
    const float* aggr = br ? aggrB : aggrA;
    const size_t outbase = br ? 573440 : 24576;

    const int row = nb_ + l15;

    bf16x8 af[8];
    af[0] = cvt8(h + (size_t)row * 64 + 8 * g);
    af[1] = cvt8(h + (size_t)row * 64 + 32 + 8 * g);
    af[2] = cvt8(aggr + (size_t)row * 64 + 8 * g);
    af[3] = cvt8(aggr + (size_t)row * 64 + 32 + 8 * g);
    if (br == 0) {
        af[4] = *(const bf16x8*)(attb + (size_t)row * 64 + 8 * g);
        af[5] = *(const bf16x8*)(attb + (size_t)row * 64 + 32 + 8 * g);
    } else {
        af[4] = (bf16x8)0;
        af[5] = (bf16x8)0;
    }
    af[6] = cvt8(orig + (size_t)row * 64 + 8 * g);
    af[7] = cvt8(orig + (size_t)row * 64 + 32 + 8 * g);

    floatx4 acc1[4];
    #pragma unroll
    for (int t = 0; t < 4; t++) acc1[t] = (floatx4)0.0f;
    #pragma unroll
    for (int c = 0; c < 8; c++) {
        #pragma unroll
        for (int t = 0; t < 4; t++) {
            bf16x8 b = *(const bf16x8*)(&W1t[(t * 16 + l15) * 256 + ((((c << 2) | g) ^ x7) << 3)]);
            acc1[t] = MFMA16(af[c], b, acc1[t]);
        }
    }
    float vv[4][4];
    #pragma unroll
    for (int t = 0; t < 4; t++)
        #pragma unroll
        for (int r = 0; r < 4; r++) vv[t][r] = acc1[t][r] + pb[t * 16 + l15];
    #pragma unroll
    for (int r = 0; r < 4; r++) {
        float s1 = vv[0][r] + vv[1][r] + vv[2][r] + vv[3][r];
        float s2 = vv[0][r] * vv[0][r] + vv[1][r] * vv[1][r] + vv[2][r] * vv[2][r] + vv[3][r] * vv[3][r];
        s1 = rowsum16(s1);
        s2 = rowsum16(s2);
        float mean = s1 * 0.015625f;
        float rstd = ln_rstd(s2, mean);
        int rw = 4 * g + r;
        int rbase = rw * 64;
        int r7 = rw & 7;
        #pragma unroll
        for (int t = 0; t < 4; t++) {
            int colx = t * 16 + l15;
            float x = (vv[t][r] - mean) * rstd * pb[64 + colx] + pb[128 + colx];
            x = lrelu(x);
            ubuf[wave][rbase + (((((t << 1) | (l15 >> 3)) ^ r7) << 3) | x7)] = (short)f2bf(x);
        }
    }
    bf16x8 a2[2];
    a2[0] = *(const bf16x8*)(&ubuf[wave][l15 * 64 + (((g) ^ x7) << 3)]);
    a2[1] = *(const bf16x8*)(&ubuf[wave][l15 * 64 + (((4 | g) ^ x7) << 3)]);
    floatx4 acc2[4];
    #pragma unroll
    for (int t = 0; t < 4; t++) acc2[t] = (floatx4)0.0f;
    #pragma unroll
    for (int c = 0; c < 2; c++) {
        #pragma unroll
        for (int t = 0; t < 4; t++) {
            bf16x8 b = *(const bf16x8*)(&W2t[(t * 16 + l15) * 64 + ((((c << 2) | g) ^ x7) << 3)]);
            acc2[t] = MFMA16(a2[c], b, acc2[t]);
        }
    }
    float u2[4][4];
    #pragma unroll
    for (int t = 0; t < 4; t++)
        #pragma unroll
        for (int r = 0; r < 4; r++) u2[t][r] = acc2[t][r] + pb[192 + t * 16 + l15];
    #pragma unroll
    for (int r = 0; r < 4; r++) {
        float s1 = u2[0][r] + u2[1][r] + u2[2][r] + u2[3][r];
        float s2 = u2[0][r] * u2[0][r] + u2[1][r] * u2[1][r] + u2[2][r] * u2[2][r] + u2[3][r] * u2[3][r];
        s1 = rowsum16(s1);
        s2 = rowsum16(s2);
        float mean = s1 * 0.015625f;
        float rstd = ln_rstd(s2, mean);
        #pragma unroll
        for (int t = 0; t < 4; t++) {
            int colx = t * 16 + l15;
            float u = (u2[t][r] - mean) * rstd * pb[256 + colx] + pb[320 + colx];
            size_t orow = (size_t)(nb_ + 4 * g + r);
            float hh = h[orow * 64 + colx];
            out[outbase + orow * 64 + colx] = 0.5f * u + 0.5f * hh;
        }
    }
}

// ---------------------------------------------------------------------------
__global__ void xnew_kernel(
    const float* __restrict__ coordsA, const float* __restrict__ origcA,
    const float* __restrict__ coordsB, const float* __restrict__ origcB,
    const float* __restrict__ xupA, const float* __restrict__ xupB,
    const int* __restrict__ rowptrA, const int* __restrict__ rowptrB,
    float* __restrict__ out)
{
    int i = blockIdx.x * 256 + threadIdx.x;   // 49152 total
    int br = (i >= 24576) ? 1 : 0;
    int j = i - br * 24576;
    const float* coords = br ? coordsB : coordsA;
    const float* origc = br ? origcB : origcA;
    const float* xup = br ? xupB : xupA;
    const int* rp = br ? rowptrB : rowptrA;
    int node = j / 3;
    float cnt = (float)(rp[node + 1] - rp[node]);
    float val = 0.25f * origc[j] + 0.75f * coords[j] + xup[j] / fmaxf(cnt, 1.0f);
    out[(br ? 548864 : 0) + j] = val;
}

// ---------------------------------------------------------------------------
extern "C" void kernel_launch(void* const* d_in, const int* in_sizes, int n_in,
                              void* d_out, int out_size, void* d_ws, size_t ws_size,
                              hipStream_t stream)
{
    int base = n_in - 29;
    for (int i = 0; i < n_in; i++) {
        if (in_sizes[i] == 11200) { base = i; break; }
    }
    const float* coordsA = (const float*)d_in[0];
    const float* hA      = (const float*)d_in[1];
    const float* origA   = (const float*)d_in[2];
    const float* origcA  = (const float*)d_in[3];
    const float* efA     = (const float*)d_in[4];
    const float* coordsB = (const float*)d_in[5];
    const float* hB      = (const float*)d_in[6];
    const float* origB   = (const float*)d_in[7];
    const float* origcB  = (const float*)d_in[8];
    const float* efB     = (const float*)d_in[9];
    const float* P[25];
    for (int k = 0; k < 25; k++) P[k] = (const float*)d_in[base + k];
    const int* srcA = (const int*)d_in[base + 25];
    const int* dstA = (const int*)d_in[base + 26];
    const int* srcB = (const int*)d_in[base + 27];
    const int* dstB = (const int*)d_in[base + 28];

    char* ws = (char*)d_ws;
    unsigned short* msgbufA = (unsigned short*)(ws + 0);          // 33.5 MB
    unsigned short* msgbufB = (unsigned short*)(ws + 33554432);   // 33.5 MB
    float* Opart  = (float*)(ws + 0);                             // 16 MB (reuse after gather)
    float* mlbuf  = (float*)(ws + 16777216);                      // 512 KB (reuse)
    unsigned short* hbA  = (unsigned short*)(ws + 67108864);      // 1 MB
    unsigned short* hbB  = (unsigned short*)(ws + 68157440);
    unsigned short* efbA = (unsigned short*)(ws + 69206016);      // 16 MB
    unsigned short* efbB = (unsigned short*)(ws + 85983232);
    float* aggrA  = (float*)(ws + 102760448);                     // 2 MB
    float* aggrB  = (float*)(ws + 104857600);
    unsigned short* qbuf = (unsigned short*)(ws + 106954752);     // 1 MB
    unsigned short* kbuf = (unsigned short*)(ws + 108003328);
    unsigned short* vTb  = (unsigned short*)(ws + 109051904);
    unsigned short* attb = (unsigned short*)(ws + 110100480);
    // zero region (one memset, 327,680 B): xupA,xupB,histA,histB,curA,curB
    float* xupA = (float*)(ws + 111149056);
    float* xupB = (float*)(ws + 111247360);
    int* histA  = (int*)(ws + 111345664);
    int* histB  = (int*)(ws + 111378432);
    int* curA   = (int*)(ws + 111411200);
    int* curB   = (int*)(ws + 111443968);
    int* rowptrA = (int*)(ws + 111476736);
    int* rowptrB = (int*)(ws + 111517696);
    int* posA   = (int*)(ws + 111558656);                          // 1 MB
    int* posB   = (int*)(ws + 112607232);                          // 1 MB
    float* out = (float*)d_out;

    hipMemsetAsync(ws + 111149056, 0, 327680, stream);

    prep_kernel<<<17408, 256, 0, stream>>>(hA, hB, efA, efB, hbA, hbB, efbA, efbB);

    hist_kernel<<<1024, 256, 0, stream>>>(dstA, dstB, histA, histB);
    scan_kernel<<<2, 1024, 0, stream>>>(histA, histB, rowptrA, rowptrB);
    scatter_kernel<<<1024, 256, 0, stream>>>(dstA, dstB, rowptrA, rowptrB,
                                             curA, curB, posA, posB);

    edge_kernel<<<1024, 512, 0, stream>>>(
        coordsA, hbA, efbA, srcA, dstA, posA,
        coordsB, hbB, efbB, srcB, dstB, posB,
        P[0], P[1], P[2], P[3], P[4], P[5], P[6], P[7],
        P[19], P[20], P[21], P[22], P[23], P[24],
        msgbufA, msgbufB, xupA, xupB);

    gather_kernel<<<2048, 256, 0, stream>>>(rowptrA, rowptrB, msgbufA, msgbufB,
                                            aggrA, aggrB);

    qkv_kernel<<<128, 256, 0, stream>>>(hbA, hbB, P[8], P[9], P[10], qbuf, kbuf, vTb);

    attn_kernel<<<1024, 256, 0, stream>>>(qbuf, kbuf, vTb, Opart, mlbuf);
    combine_kernel<<<2048, 256, 0, stream>>>(Opart, mlbuf, attb);

    node_kernel<<<256, 256, 0, stream>>>(
        hA, hB, origA, origB, attb, aggrA, aggrB,
        P[11], P[12], P[13], P[14], P[15], P[16], P[17], P[18], out);

    xnew_kernel<<<192, 256, 0, stream>>>(
        coordsA, origcA, coordsB, origcB, xupA, xupB, rowptrA, rowptrB, out);
}

// Round 7
// 763.425 us; speedup vs baseline: 1.2993x; 1.2993x over previous
//
#include <hip/hip_runtime.h>
#include <cstdint>
#include <cstddef>

// ---------------------------------------------------------------------------
// Fine_Grain_Layer. f32 I/O, bf16 MFMA operands, f32 accumulate.
// R14 -> R15: REVERT to R13 (best, 765.5us). R14 (transposed LN1+LN2)
// spilled (FETCH 769MB, WRITE 434MB, edge 388us) even without the
// persistent grid -> root cause identified: transposed LN needs params at
// t*16+4g+r for ALL t,r = 16 hoisted floats/lane per param vector (vs 4 in
// row-form). LN1+LN2+coef = 10 vectors -> ~160 LICM-hoisted regs -> past
// the 128-reg cliff. R12's spill is re-attributed to the same mechanism.
// The coef-only transpose (R13) fits because it deletes w3[16] + 50
// shuffles while adding 64 hoisted floats (net ~neutral). LN transposes
// are structurally register-positive -- lever exhausted; R13 edge is the
// register-pressure sweet spot. R15 adds ONE riskless change: node_kernel
// f32 loads vectorized (cvt8 8-scalar-loads -> 2x float4, G13), separate
// kernel/register budget, cannot affect edge.
// ~162 us of dur is the harness's 1 GiB ws poison fill; several hundred
// more us are the harness reset()'s tiny restore dispatches (both
// uncontrollable).
// ---------------------------------------------------------------------------

typedef short bf16x8 __attribute__((ext_vector_type(8)));
typedef float floatx4 __attribute__((ext_vector_type(4)));

#define MFMA16(a, b, c) __builtin_amdgcn_mfma_f32_16x16x32_bf16((a), (b), (c), 0, 0, 0)

__device__ __forceinline__ unsigned short f2bf(float f) {
    unsigned int u = __builtin_bit_cast(unsigned int, f);
    u += 0x7fffu + ((u >> 16) & 1u);   // round to nearest even
    return (unsigned short)(u >> 16);
}
__device__ __forceinline__ float bf2f(unsigned short u) {
    unsigned int x = ((unsigned int)u) << 16;
    return __builtin_bit_cast(float, x);
}
__device__ __forceinline__ bf16x8 cvt8v(const float* __restrict__ p) {
    float4 a = *(const float4*)p;
    float4 b = *(const float4*)(p + 4);
    bf16x8 r;
    r[0] = (short)f2bf(a.x); r[1] = (short)f2bf(a.y);
    r[2] = (short)f2bf(a.z); r[3] = (short)f2bf(a.w);
    r[4] = (short)f2bf(b.x); r[5] = (short)f2bf(b.y);
    r[6] = (short)f2bf(b.z); r[7] = (short)f2bf(b.w);
    return r;
}
__device__ __forceinline__ float rowsum16(float x) {
    x += __shfl_xor(x, 1);
    x += __shfl_xor(x, 2);
    x += __shfl_xor(x, 4);
    x += __shfl_xor(x, 8);
    return x;
}
__device__ __forceinline__ float rowmax16(float x) {
    x = fmaxf(x, __shfl_xor(x, 1));
    x = fmaxf(x, __shfl_xor(x, 2));
    x = fmaxf(x, __shfl_xor(x, 4));
    x = fmaxf(x, __shfl_xor(x, 8));
    return x;
}
__device__ __forceinline__ float lrelu(float x) { return x > 0.f ? x : 0.01f * x; }
__device__ __forceinline__ float ln_rstd(float s2, float mean) {
    float var = s2 * 0.015625f - mean * mean;
    return rsqrtf(fmaxf(var, 0.0f) + 1e-5f);
}

__constant__ float INVSIG[16] = {
    1.0f, 0.6666666865f, 0.4444444597f, 0.2962962985f, 0.1975308657f,
    0.1316872428f, 0.0877914950f, 0.0585276633f, 0.0390184447f, 0.0260122959f,
    0.0173415299f, 0.0115610203f, 0.0077073467f, 0.0051382311f, 0.0034254875f, 0.0f};

// ---------------------------------------------------------------------------
// Pre-convert h (2x524288) and ef (2x8388608) to bf16. Quad-granular.
__global__ void prep_kernel(const float* __restrict__ hA, const float* __restrict__ hB,
                            const float* __restrict__ efA, const float* __restrict__ efB,
                            unsigned short* __restrict__ hbA, unsigned short* __restrict__ hbB,
                            unsigned short* __restrict__ efbA, unsigned short* __restrict__ efbB)
{
    int q = blockIdx.x * 256 + threadIdx.x;   // 4,456,448 quads exactly
    const float* s; unsigned short* d; int off;
    if (q < 131072)        { s = hA;  d = hbA;  off = q; }
    else if (q < 262144)   { s = hB;  d = hbB;  off = q - 131072; }
    else if (q < 2359296)  { s = efA; d = efbA; off = q - 262144; }
    else                   { s = efB; d = efbB; off = q - 2359296; }
    float4 v = *(const float4*)(s + (size_t)off * 4);
    ushort4 o;
    o.x = f2bf(v.x); o.y = f2bf(v.y); o.z = f2bf(v.z); o.w = f2bf(v.w);
    *(ushort4*)(d + (size_t)off * 4) = o;
}

// ---------------------------------------------------------------------------
__global__ void hist_kernel(const int* __restrict__ dstA, const int* __restrict__ dstB,
                            int* __restrict__ histA, int* __restrict__ histB)
{
    int e = blockIdx.x * 256 + threadIdx.x;   // exactly 262144
    atomicAdd(&histA[dstA[e]], 1);
    atomicAdd(&histB[dstB[e]], 1);
}

__global__ void scan_kernel(const int* __restrict__ histA, const int* __restrict__ histB,
                            int* __restrict__ rowptrA, int* __restrict__ rowptrB)
{
    const int b = blockIdx.x;   // 0 = A, 1 = B
    const int* hist = b ? histB : histA;
    int* rowptr = b ? rowptrB : rowptrA;
    __shared__ int part[1024];
    int t = threadIdx.x;
    int v[8]; int s = 0;
    #pragma unroll
    for (int j = 0; j < 8; j++) { v[j] = hist[t * 8 + j]; s += v[j]; }
    part[t] = s;
    __syncthreads();
    for (int off = 1; off < 1024; off <<= 1) {
        int x = part[t];
        int y = (t >= off) ? part[t - off] : 0;
        __syncthreads();
        part[t] = x + y;
        __syncthreads();
    }
    int run = (t > 0) ? part[t - 1] : 0;
    #pragma unroll
    for (int j = 0; j < 8; j++) { rowptr[t * 8 + j] = run; run += v[j]; }
    if (t == 1023) rowptr[8192] = run;
}

// pos[e] = slot of edge e in dst-CSR order
__global__ void scatter_kernel(const int* __restrict__ dstA, const int* __restrict__ dstB,
                               const int* __restrict__ rowptrA, const int* __restrict__ rowptrB,
                               int* __restrict__ curA, int* __restrict__ curB,
                               int* __restrict__ posA, int* __restrict__ posB)
{
    int e = blockIdx.x * 256 + threadIdx.x;   // exactly 262144
    int dA = dstA[e];
    posA[e] = rowptrA[dA] + atomicAdd(&curA[dA], 1);
    int dB = dstB[e];
    posB[e] = rowptrB[dB] + atomicAdd(&curB[dB], 1);
}

// ---------------------------------------------------------------------------
// Edge kernel, both branches: one wave = 16 edges; 8 waves/block; barrier-free
// body. bf16 inputs; msg rows written at CSR slot pos[e].
// Minimal prefetch: next iter's idx (3 ints) + ef (1 bf16x8) only.
// LN1/LN2 row-form (register-cheap); coef MLP transposed-C (register-neutral).
__global__ __launch_bounds__(512, 2) void edge_kernel(
    const float* __restrict__ coordsA, const unsigned short* __restrict__ hbA,
    const unsigned short* __restrict__ efbA, const int* __restrict__ srcA,
    const int* __restrict__ dstA, const int* __restrict__ posA,
    const float* __restrict__ coordsB, const unsigned short* __restrict__ hbB,
    const unsigned short* __restrict__ efbB, const int* __restrict__ srcB,
    const int* __restrict__ dstB, const int* __restrict__ posB,
    const float* __restrict__ eW1, const float* __restrict__ eb1,
    const float* __restrict__ eg1, const float* __restrict__ ebt1,
    const float* __restrict__ eW2, const float* __restrict__ eb2,
    const float* __restrict__ eg2, const float* __restrict__ ebt2,
    const float* __restrict__ cW1, const float* __restrict__ cb1,
    const float* __restrict__ cg1, const float* __restrict__ cbt1,
    const float* __restrict__ cW2, const float* __restrict__ cb2,
    unsigned short* __restrict__ msgbufA, unsigned short* __restrict__ msgbufB,
    float* __restrict__ xupA, float* __restrict__ xupB)
{
    // XOR-swizzled LDS tiles: addr = row*stride + ((blk ^ (row&7))<<3) + (col&7)
    __shared__ __attribute__((aligned(16))) short Wt1[64 * 192];   // 24576 B
    __shared__ __attribute__((aligned(16))) short Wt2s[64 * 64];   //  8192 B
    __shared__ __attribute__((aligned(16))) short Wc1s[64 * 64];   //  8192 B
    __shared__ __attribute__((aligned(16))) float pb[644];         //  2576 B
    __shared__ __attribute__((aligned(16))) short msgb[8][16 * 64];// 16384 B -> 59920 total

    const int tid = threadIdx.x;

    for (int i = tid; i < 64 * 192; i += 512) {
        int n = i / 192, kk = i - n * 192;
        float w = (kk < 175) ? eW1[kk * 64 + n] : 0.0f;
        Wt1[n * 192 + ((((kk >> 3) ^ (n & 7)) << 3) | (kk & 7))] = (short)f2bf(w);
    }
    for (int i = tid; i < 4096; i += 512) {
        int n = i >> 6, kk = i & 63;
        int o = n * 64 + ((((kk >> 3) ^ (n & 7)) << 3) | (kk & 7));
        Wt2s[o] = (short)f2bf(eW2[kk * 64 + n]);
        Wc1s[o] = (short)f2bf(cW1[kk * 64 + n]);
    }
    if (tid < 64) {
        pb[tid]       = eb1[tid];
        pb[64 + tid]  = eg1[tid];
        pb[128 + tid] = ebt1[tid];
        pb[192 + tid] = eb2[tid];
        pb[256 + tid] = eg2[tid];
        pb[320 + tid] = ebt2[tid];
        pb[384 + tid] = cb1[tid];
        pb[448 + tid] = cg1[tid];
        pb[512 + tid] = cbt1[tid];
        pb[576 + tid] = cW2[tid];
    }
    if (tid == 0) pb[640] = cb2[0];
    __syncthreads();   // the ONLY barrier

    const int wave = tid >> 6;
    const int lane = tid & 63;
    const int l15 = lane & 15;
    const int g = lane >> 4;
    const int x7 = l15 & 7;
    const int gi0 = blockIdx.x * 8 + wave;   // < 8192

    // iteration it (0..3): branch = it>>1; in-branch edge base alternates
    // between eA0 (it 0,2) and eA1 (it 1,3).
    const int eA0 = (gi0 & 16383) * 16 + l15;
    const int eA1 = eA0 + 8192 * 16;

    // prefetch it=0 (branch A, edge eA0)
    int s_n  = srcA[eA0];
    int d_n  = dstA[eA0];
    int sl_n = posA[eA0];
    bf16x8 ef_n = *(const bf16x8*)(efbA + (size_t)eA0 * 32 + 8 * g);

    #pragma unroll 1
    for (int it = 0; it < 4; ++it) {
        const int br = it >> 1;
        const float* coords = br ? coordsB : coordsA;
        const unsigned short* hb = br ? hbB : hbA;
        unsigned short* msgbuf = br ? msgbufB : msgbufA;
        float* xup = br ? xupB : xupA;

        const int s = s_n, d0 = d_n, slot = sl_n;
        const bf16x8 ef = ef_n;

        // current-iteration dependent loads: issue ASAP
        bf16x8 h0 = *(const bf16x8*)(hb + (size_t)s * 64 + 8 * g);
        bf16x8 h1 = *(const bf16x8*)(hb + (size_t)s * 64 + 32 + 8 * g);
        bf16x8 h2 = *(const bf16x8*)(hb + (size_t)d0 * 64 + 8 * g);
        bf16x8 h3 = *(const bf16x8*)(hb + (size_t)d0 * 64 + 32 + 8 * g);
        float cs0 = coords[s * 3 + 0];
        float cs1 = coords[s * 3 + 1];
        float cs2 = coords[s * 3 + 2];
        float cd0 = coords[d0 * 3 + 0];
        float cd1 = coords[d0 * 3 + 1];
        float cd2 = coords[d0 * 3 + 2];

        // prefetch next iteration's idx + ef (addresses independent of above)
        if (it < 3) {
            const int brn = (it + 1) >> 1;
            const int en = (it & 1) ? eA0 : eA1;
            const int* srcN = brn ? srcB : srcA;
            const int* dstN = brn ? dstB : dstA;
            const int* posN = brn ? posB : posA;
            const unsigned short* efbN = brn ? efbB : efbA;
            s_n  = srcN[en];
            d_n  = dstN[en];
            sl_n = posN[en];
            ef_n = *(const bf16x8*)(efbN + (size_t)en * 32 + 8 * g);
        }

        const float xr0 = cs0 - cd0;
        const float xr1 = cs1 - cd1;
        const float xr2 = cs2 - cd2;
        const float d2 = xr0 * xr0 + xr1 * xr1 + xr2 * xr2;

        bf16x8 af5;
        #pragma unroll
        for (int j = 0; j < 8; j++) {
            int idx = 8 * g + j;
            float rv = 0.0f;
            if (g < 2 && idx < 15) rv = __expf(-d2 * INVSIG[idx & 15]);
            af5[j] = (short)f2bf(rv);
        }

        // layer 1: [16 x 192] @ [192 x 64]
        floatx4 acc1[4];
        #pragma unroll
        for (int t = 0; t < 4; t++) acc1[t] = (floatx4)0.0f;
        {
            bf16x8 af[6] = {h0, h1, h2, h3, ef, af5};
            #pragma unroll
            for (int c = 0; c < 6; c++) {
                #pragma unroll
                for (int t = 0; t < 4; t++) {
                    bf16x8 b = *(const bf16x8*)(&Wt1[(t * 16 + l15) * 192 + ((((c << 2) | g) ^ x7) << 3)]);
                    acc1[t] = MFMA16(af[c], b, acc1[t]);
                }
            }
        }

        float vv[4][4];
        #pragma unroll
        for (int t = 0; t < 4; t++)
            #pragma unroll
            for (int r = 0; r < 4; r++) vv[t][r] = acc1[t][r] + pb[t * 16 + l15];
        #pragma unroll
        for (int r = 0; r < 4; r++) {
            float s1 = vv[0][r] + vv[1][r] + vv[2][r] + vv[3][r];
            float s2 = vv[0][r] * vv[0][r] + vv[1][r] * vv[1][r] + vv[2][r] * vv[2][r] + vv[3][r] * vv[3][r];
            s1 = rowsum16(s1);
            s2 = rowsum16(s2);
            float mean = s1 * 0.015625f;
            float rstd = ln_rstd(s2, mean);
            int row = 4 * g + r;
            int rbase = row * 64;
            int r7 = row & 7;
            #pragma unroll
            for (int t = 0; t < 4; t++) {
                int colx = t * 16 + l15;
                float x = (vv[t][r] - mean) * rstd * pb[64 + colx] + pb[128 + colx];
                x = lrelu(x);
                msgb[wave][rbase + (((((t << 1) | (l15 >> 3)) ^ r7) << 3) | x7)] = (short)f2bf(x);
            }
        }

        // layer 2: [16 x 64] @ [64 x 64] -> msg (LN, no lrelu)
        bf16x8 a2[2];
        a2[0] = *(const bf16x8*)(&msgb[wave][l15 * 64 + (((g) ^ x7) << 3)]);
        a2[1] = *(const bf16x8*)(&msgb[wave][l15 * 64 + (((4 | g) ^ x7) << 3)]);
        floatx4 acc2[4];
        #pragma unroll
        for (int t = 0; t < 4; t++) acc2[t] = (floatx4)0.0f;
        #pragma unroll
        for (int c = 0; c < 2; c++) {
            #pragma unroll
            for (int t = 0; t < 4; t++) {
                bf16x8 b = *(const bf16x8*)(&Wt2s[(t * 16 + l15) * 64 + ((((c << 2) | g) ^ x7) << 3)]);
                acc2[t] = MFMA16(a2[c], b, acc2[t]);
            }
        }
        float vm[4][4];
        #pragma unroll
        for (int t = 0; t < 4; t++)
            #pragma unroll
            for (int r = 0; r < 4; r++) vm[t][r] = acc2[t][r] + pb[192 + t * 16 + l15];
        #pragma unroll
        for (int r = 0; r < 4; r++) {
            float s1 = vm[0][r] + vm[1][r] + vm[2][r] + vm[3][r];
            float s2 = vm[0][r] * vm[0][r] + vm[1][r] * vm[1][r] + vm[2][r] * vm[2][r] + vm[3][r] * vm[3][r];
            s1 = rowsum16(s1);
            s2 = rowsum16(s2);
            float mean = s1 * 0.015625f;
            float rstd = ln_rstd(s2, mean);
            #pragma unroll
            for (int t = 0; t < 4; t++) {
                int colx = t * 16 + l15;
                vm[t][r] = (vm[t][r] - mean) * rstd * pb[256 + colx] + pb[320 + colx];
            }
        }
        #pragma unroll
        for (int r = 0; r < 4; r++) {
            int row = 4 * g + r;
            int rbase = row * 64;
            int r7 = row & 7;
            #pragma unroll
            for (int t = 0; t < 4; t++)
                msgb[wave][rbase + (((((t << 1) | (l15 >> 3)) ^ r7) << 3) | x7)] = (short)f2bf(vm[t][r]);
        }

        // single re-read of final msg fragments: reused for the global store
        // AND as the coef-MLP B-operand (transposed MFMA).
        bf16x8 m0 = *(const bf16x8*)(&msgb[wave][l15 * 64 + (((g) ^ x7) << 3)]);
        bf16x8 m1 = *(const bf16x8*)(&msgb[wave][l15 * 64 + (((4 | g) ^ x7) << 3)]);
        {
            unsigned short* mrow = msgbuf + (size_t)slot * 64;
            *(bf16x8*)(mrow + 8 * g)      = m0;
            *(bf16x8*)(mrow + 32 + 8 * g) = m1;
        }

        // coef MLP, TRANSPOSED-C: W-frag as A-operand, msg-frag as B-operand.
        // acc3[t][r] = coef-layer feature (16t+4g+r) of edge l15. LN stats
        // reduce across g-groups (shfl_xor 16/32); cW2 dot in-lane; every
        // lane ends holding coef of its own edge l15 (no redistribute).
        floatx4 acc3[4];
        #pragma unroll
        for (int t = 0; t < 4; t++) acc3[t] = (floatx4)0.0f;
        #pragma unroll
        for (int c = 0; c < 2; c++) {
            #pragma unroll
            for (int t = 0; t < 4; t++) {
                bf16x8 b = *(const bf16x8*)(&Wc1s[(t * 16 + l15) * 64 + ((((c << 2) | g) ^ x7) << 3)]);
                acc3[t] = MFMA16(b, c == 0 ? m0 : m1, acc3[t]);
            }
        }
        float cf;
        {
            float s1 = 0.f, s2 = 0.f;
            #pragma unroll
            for (int t = 0; t < 4; t++) {
                const floatx4 bv = *(const floatx4*)&pb[384 + t * 16 + 4 * g];
                #pragma unroll
                for (int r = 0; r < 4; r++) {
                    float x = acc3[t][r] + bv[r];
                    acc3[t][r] = x;
                    s1 += x; s2 += x * x;
                }
            }
            s1 += __shfl_xor(s1, 16); s1 += __shfl_xor(s1, 32);
            s2 += __shfl_xor(s2, 16); s2 += __shfl_xor(s2, 32);
            const float mean = s1 * 0.015625f;
            const float rstd = ln_rstd(s2, mean);
            float p = 0.f;
            #pragma unroll
            for (int t = 0; t < 4; t++) {
                const floatx4 gv = *(const floatx4*)&pb[448 + t * 16 + 4 * g];
                const floatx4 bt = *(const floatx4*)&pb[512 + t * 16 + 4 * g];
                const floatx4 wv = *(const floatx4*)&pb[576 + t * 16 + 4 * g];
                #pragma unroll
                for (int r = 0; r < 4; r++) {
                    float x = (acc3[t][r] - mean) * rstd * gv[r] + bt[r];
                    p += lrelu(x) * wv[r];
                }
            }
            p += __shfl_xor(p, 16); p += __shfl_xor(p, 32);
            cf = p + pb[640];       // every lane: coef of its edge l15
        }

        if (g < 3) {
            float xrg = (g == 0) ? xr0 : (g == 1) ? xr1 : xr2;
            atomicAdd(&xup[(size_t)d0 * 3 + g], xrg * cf);
        }
    }
}

// ---------------------------------------------------------------------------
// Gather-reduce over CSR-ordered msgbuf: contiguous streaming reads.
__global__ __launch_bounds__(256, 4) void gather_kernel(
    const int* __restrict__ rowptrA, const int* __restrict__ rowptrB,
    const unsigned short* __restrict__ msgbufA, const unsigned short* __restrict__ msgbufB,
    float* __restrict__ aggrA, float* __restrict__ aggrB)
{
    const int tid = threadIdx.x;
    const int wave = tid >> 6, lane = tid & 63;
    const int nwaves = gridDim.x * 4;
    for (int u = blockIdx.x * 4 + wave; u < 16384; u += nwaves) {
        const int br = u >> 13;
        const int n = u & 8191;
        const int* rowptr = br ? rowptrB : rowptrA;
        const unsigned short* mb = br ? msgbufB : msgbufA;
        float* aggr = br ? aggrB : aggrA;
        int base = rowptr[n];
        int deg = rowptr[n + 1] - base;
        float a[8];
        #pragma unroll
        for (int j = 0; j < 8; j++) a[j] = 0.f;
        int i = 0;
        for (; i + 8 <= deg; i += 8) {
            #pragma unroll
            for (int j = 0; j < 8; j++)
                a[j] += bf2f(mb[(size_t)(base + i + j) * 64 + lane]);
        }
        for (; i < deg; i++) a[0] += bf2f(mb[(size_t)(base + i) * 64 + lane]);
        float t = (a[0] + a[1]) + (a[2] + a[3]) + ((a[4] + a[5]) + (a[6] + a[7]));
        aggr[(size_t)n * 64 + lane] = t / fmaxf((float)deg, 1.0f);
    }
}

// ---------------------------------------------------------------------------
__global__ __launch_bounds__(256, 2) void qkv_kernel(
    const unsigned short* __restrict__ hbA, const unsigned short* __restrict__ hbB,
    const float* __restrict__ qW, const float* __restrict__ kW,
    const float* __restrict__ vW,
    unsigned short* __restrict__ qo, unsigned short* __restrict__ ko,
    unsigned short* __restrict__ vTo)
{
    __shared__ __attribute__((aligned(16))) short Wq[64 * 64];
    __shared__ __attribute__((aligned(16))) short Wk[64 * 64];
    __shared__ __attribute__((aligned(16))) short Wv[64 * 64];
    const int tid = threadIdx.x;
    for (int i = tid; i < 4096; i += 256) {
        int n = i >> 6, kk = i & 63;
        int o = n * 64 + ((((kk >> 3) ^ (n & 7)) << 3) | (kk & 7));
        Wq[o] = (short)f2bf(qW[kk * 64 + n]);
        Wk[o] = (short)f2bf(kW[kk * 64 + n]);
        Wv[o] = (short)f2bf(vW[kk * 64 + n]);
    }
    __syncthreads();
    const int wave = tid >> 6, lane = tid & 63, l15 = lane & 15, g = lane >> 4;
    const int x7 = l15 & 7;
    const int row0 = blockIdx.x * 64 + wave * 16;
    bf16x8 aA[2], aB[2];
    aA[0] = *(const bf16x8*)(hbA + (size_t)(row0 + l15) * 64 + 8 * g);
    aA[1] = *(const bf16x8*)(hbA + (size_t)(row0 + l15) * 64 + 32 + 8 * g);
    aB[0] = *(const bf16x8*)(hbB + (size_t)(row0 + l15) * 64 + 8 * g);
    aB[1] = *(const bf16x8*)(hbB + (size_t)(row0 + l15) * 64 + 32 + 8 * g);
    floatx4 aq[4], ak4[4], av[4];
    #pragma unroll
    for (int t = 0; t < 4; t++) { aq[t] = (floatx4)0.0f; ak4[t] = (floatx4)0.0f; av[t] = (floatx4)0.0f; }
    #pragma unroll
    for (int c = 0; c < 2; c++) {
        #pragma unroll
        for (int t = 0; t < 4; t++) {
            int wo = (t * 16 + l15) * 64 + ((((c << 2) | g) ^ x7) << 3);
            aq[t] = MFMA16(aA[c], *(const bf16x8*)(&Wq[wo]), aq[t]);
            ak4[t] = MFMA16(aB[c], *(const bf16x8*)(&Wk[wo]), ak4[t]);
            av[t] = MFMA16(aB[c], *(const bf16x8*)(&Wv[wo]), av[t]);
        }
    }
    #pragma unroll
    for (int t = 0; t < 4; t++) {
        #pragma unroll
        for (int r = 0; r < 4; r++) {
            int orow = row0 + 4 * g + r, ocol = t * 16 + l15;
            qo[(size_t)orow * 64 + ocol] = f2bf(lrelu(aq[t][r]));
            ko[(size_t)orow * 64 + ocol] = f2bf(lrelu(ak4[t][r]));
            vTo[(size_t)ocol * 8192 + orow] = f2bf(av[t][r]);   // v transposed
        }
    }
}

// ---------------------------------------------------------------------------
// Flash attention, K-split=8, direct L2 b-frag loads, no barriers.
__global__ __launch_bounds__(256, 4) void attn_kernel(
    const unsigned short* __restrict__ qb_, const unsigned short* __restrict__ kb_,
    const unsigned short* __restrict__ vT,
    float* __restrict__ Opart, float* __restrict__ ml)
{
    __shared__ __attribute__((aligned(16))) short pbuf[4][16 * 64];
    const int tid = threadIdx.x;
    const int wave = tid >> 6, lane = tid & 63, l15 = lane & 15, g = lane >> 4;
    const int x7 = l15 & 7;
    const int qblock = blockIdx.x >> 3;         // 128 q-blocks
    const int split = blockIdx.x & 7;           // 8 k-splits
    const int qrow0 = qblock * 64 + wave * 16;
    const int kbase = split * 1024;
    bf16x8 qf[2];
    qf[0] = *(const bf16x8*)(qb_ + (size_t)(qrow0 + l15) * 64 + 8 * g);
    qf[1] = *(const bf16x8*)(qb_ + (size_t)(qrow0 + l15) * 64 + 32 + 8 * g);
    float m_[4], l_[4];
    floatx4 oacc[4];
    #pragma unroll
    for (int r = 0; r < 4; r++) { m_[r] = -1.0e30f; l_[r] = 0.f; }
    #pragma unroll
    for (int t = 0; t < 4; t++) oacc[t] = (floatx4)0.0f;

    for (int kt = 0; kt < 16; kt++) {
        const int krow0 = kbase + kt * 64;
        floatx4 sacc[4];
        #pragma unroll
        for (int t = 0; t < 4; t++) sacc[t] = (floatx4)0.0f;
        #pragma unroll
        for (int c = 0; c < 2; c++) {
            #pragma unroll
            for (int t = 0; t < 4; t++) {
                bf16x8 b = *(const bf16x8*)(kb_ + (size_t)(krow0 + t * 16 + l15) * 64 + 32 * c + 8 * g);
                sacc[t] = MFMA16(qf[c], b, sacc[t]);
            }
        }
        #pragma unroll
        for (int r = 0; r < 4; r++) {
            float mx = fmaxf(fmaxf(sacc[0][r], sacc[1][r]), fmaxf(sacc[2][r], sacc[3][r]));
            mx = rowmax16(mx);
            float mn = fmaxf(m_[r], mx);
            float sc = __expf(fminf(m_[r] - mn, 0.f));
            float ps = 0.f;
            int row = 4 * g + r;
            int rbase = row * 64;
            int r7 = row & 7;
            #pragma unroll
            for (int t = 0; t < 4; t++) {
                float p = __expf(fminf(sacc[t][r] - mn, 0.f));
                ps += p;
                pbuf[wave][rbase + (((((t << 1) | (l15 >> 3)) ^ r7) << 3) | x7)] = (short)f2bf(p);
            }
            ps = rowsum16(ps);
            l_[r] = l_[r] * sc + ps;
            m_[r] = mn;
            #pragma unroll
            for (int t = 0; t < 4; t++) oacc[t][r] *= sc;
        }
        bf16x8 pf[2];
        pf[0] = *(const bf16x8*)(&pbuf[wave][l15 * 64 + (((g) ^ x7) << 3)]);
        pf[1] = *(const bf16x8*)(&pbuf[wave][l15 * 64 + (((4 | g) ^ x7) << 3)]);
        #pragma unroll
        for (int c = 0; c < 2; c++) {
            #pragma unroll
            for (int t = 0; t < 4; t++) {
                bf16x8 b = *(const bf16x8*)(vT + (size_t)(t * 16 + l15) * 8192 + krow0 + 32 * c + 8 * g);
                oacc[t] = MFMA16(pf[c], b, oacc[t]);
            }
        }
    }
    #pragma unroll
    for (int t = 0; t < 4; t++) {
        #pragma unroll
        for (int r = 0; r < 4; r++) {
            int row = qrow0 + 4 * g + r;
            Opart[((size_t)split * 8192 + row) * 64 + t * 16 + l15] = oacc[t][r];
        }
    }
    if (l15 == 0) {
        #pragma unroll
        for (int r = 0; r < 4; r++) {
            int row = qrow0 + 4 * g + r;
            ml[((size_t)split * 8192 + row) * 2 + 0] = m_[r];
            ml[((size_t)split * 8192 + row) * 2 + 1] = l_[r];
        }
    }
}

__global__ void combine_kernel(const float* __restrict__ Opart, const float* __restrict__ ml,
                               unsigned short* __restrict__ attb)
{
    int idx = blockIdx.x * 256 + threadIdx.x;   // 8192*64
    int row = idx >> 6, col = idx & 63;
    float mm = -1.0e30f;
    #pragma unroll
    for (int s = 0; s < 8; s++) mm = fmaxf(mm, ml[((size_t)s * 8192 + row) * 2]);
    float l = 0.f, o = 0.f;
    #pragma unroll
    for (int s = 0; s < 8; s++) {
        float w = __expf(ml[((size_t)s * 8192 + row) * 2] - mm);
        l += w * ml[((size_t)s * 8192 + row) * 2 + 1];
        o += w * Opart[((size_t)s * 8192 + row) * 64 + col];
    }
    attb[(size_t)row * 64 + col] = f2bf(o / l);
}

// ---------------------------------------------------------------------------
__global__ __launch_bounds__(256, 2) void node_kernel(
    const float* __restrict__ hA, const float* __restrict__ hB,
    const float* __restrict__ origA, const float* __restrict__ origB,
    const unsigned short* __restrict__ attb,
    const float* __restrict__ aggrA, const float* __restrict__ aggrB,
    const float* __restrict__ nW1, const float* __restrict__ nb1,
    const float* __restrict__ ng1, const float* __restrict__ nbt1,
    const float* __restrict__ nW2, const float* __restrict__ nb2,
    const float* __restrict__ ng2, const float* __restrict__ nbt2,
    float* __restrict__ out)
{
    __shared__ __attribute__((aligned(16))) short W1t[64 * 256];
    __shared__ __attribute__((aligned(16))) short W2t[64 * 64];
    __shared__ __attribute__((aligned(16))) float pb[6 * 64];
    __shared__ __attribute__((aligned(16))) short ubuf[4][16 * 64];
    const int tid = threadIdx.x;
    for (int i = tid; i < 64 * 256; i += 256) {
        int n = i >> 8, kk = i & 255;
        W1t[n * 256 + ((((kk >> 3) ^ (n & 7)) << 3) | (kk & 7))] = (short)f2bf(nW1[kk * 64 + n]);
    }
    for (int i = tid; i < 4096; i += 256) {
        int n = i >> 6, kk = i & 63;
        W2t[n * 64 + ((((kk >> 3) ^ (n & 7)) << 3) | (kk & 7))] = (short)f2bf(nW2[kk * 64 + n]);
    }
    if (tid < 64) {
        pb[tid]       = nb1[tid];
        pb[64 + tid]  = ng1[tid];
        pb[128 + tid] = nbt1[tid];
        pb[192 + tid] = nb2[tid];
        pb[256 + tid] = ng2[tid];
        pb[320 + tid] = nbt2[tid];
    }
    __syncthreads();   // only barrier
    const int wave = tid >> 6, lane = tid & 63, l15 = lane & 15, g = lane >> 4;
    const int x7 = l15 & 7;
    const int unit = blockIdx.x * 4 + wave;          // 1024 units
    const int br = unit >> 9;
    const int nb_ = (unit & 511) * 16;
    const float* h = br ? hB : hA;
    const float* orig = br ? origB : origA;
    const float* aggr = br ? aggrB : aggrA;
    const size_t outbase = br ? 573440 : 24576;

    const int row = nb_ + l15;

    bf16x8 af[8];
    af[0] = cvt8v(h + (size_t)row * 64 + 8 * g);
    af[1] = cvt8v(h + (size_t)row * 64 + 32 + 8 * g);
    af[2] = cvt8v(aggr + (size_t)row * 64 + 8 * g);
    af[3] = cvt8v(aggr + (size_t)row * 64 + 32 + 8 * g);
    if (br == 0) {
        af[4] = *(const bf16x8*)(attb + (size_t)row * 64 + 8 * g);
        af[5] = *(const bf16x8*)(attb + (size_t)row * 64 + 32 + 8 * g);
    } else {
        af[4] = (bf16x8)0;
        af[5] = (bf16x8)0;
    }
    af[6] = cvt8v(orig + (size_t)row * 64 + 8 * g);
    af[7] = cvt8v(orig + (size_t)row * 64 + 32 + 8 * g);

    floatx4 acc1[4];
    #pragma unroll
    for (int t = 0; t < 4; t++) acc1[t] = (floatx4)0.0f;
    #pragma unroll
    for (int c = 0; c < 8; c++) {
        #pragma unroll
        for (int t = 0; t < 4; t++) {
            bf16x8 b = *(const bf16x8*)(&W1t[(t * 16 + l15) * 256 + ((((c << 2) | g) ^ x7) << 3)]);
            acc1[t] = MFMA16(af[c], b, acc1[t]);
        }
    }
    float vv[4][4];
    #pragma unroll
    for (int t = 0; t < 4; t++)
        #pragma unroll
        for (int r = 0; r < 4; r++) vv[t][r] = acc1[t][r] + pb[t * 16 + l15];
    #pragma unroll
    for (int r = 0; r < 4; r++) {
        float s1 = vv[0][r] + vv[1][r] + vv[2][r] + vv[3][r];
        float s2 = vv[0][r] * vv[0][r] + vv[1][r] * vv[1][r] + vv[2][r] * vv[2][r] + vv[3][r] * vv[3][r];
        s1 = rowsum16(s1);
        s2 = rowsum16(s2);
        float mean = s1 * 0.015625f;
        float rstd = ln_rstd(s2, mean);
        int rw = 4 * g + r;
        int rbase = rw * 64;
        int r7 = rw & 7;
        #pragma unroll
        for (int t = 0; t < 4; t++) {
            int colx = t * 16 + l15;
            float x = (vv[t][r] - mean) * rstd * pb[64 + colx] + pb[128 + colx];
            x = lrelu(x);
            ubuf[wave][rbase + (((((t << 1) | (l15 >> 3)) ^ r7) << 3) | x7)] = (short)f2bf(x);
        }
    }
    bf16x8 a2[2];
    a2[0] = *(const bf16x8*)(&ubuf[wave][l15 * 64 + (((g) ^ x7) << 3)]);
    a2[1] = *(const bf16x8*)(&ubuf[wave][l15 * 64 + (((4 | g) ^ x7) << 3)]);
    floatx4 acc2[4];
    #pragma unroll
    for (int t = 0; t < 4; t++) acc2[t] = (floatx4)0.0f;
    #pragma unroll
    for (int c = 0; c < 2; c++) {
        #pragma unroll
        for (int t = 0; t < 4; t++) {
            bf16x8 b = *(const bf16x8*)(&W2t[(t * 16 + l15) * 64 + ((((c << 2) | g) ^ x7) << 3)]);
            acc2[t] = MFMA16(a2[c], b, acc2[t]);
        }
    }
    float u2[4][4];
    #pragma unroll
    for (int t = 0; t < 4; t++)
        #pragma unroll
        for (int r = 0; r < 4; r++) u2[t][r] = acc2[t][r] + pb[192 + t * 16 + l15];
    #pragma unroll
    for (int r = 0; r < 4; r++) {
        float s1 = u2[0][r] + u2[1][r] + u2[2][r] + u2[3][r];
        float s2 = u2[0][r] * u2[0][r] + u2[1][r] * u2[1][r] + u2[2][r] * u2[2][r] + u2[3][r] * u2[3][r];
        s1 = rowsum16(s1);
        s2 = rowsum16(s2);
        float mean = s1 * 0.015625f;
        float rstd = ln_rstd(s2, mean);
        #pragma unroll
        for (int t = 0; t < 4; t++) {
            int colx = t * 16 + l15;
            float u = (u2[t][r] - mean) * rstd * pb[256 + colx] + pb[320 + colx];
            size_t orow = (size_t)(nb_ + 4 * g + r);
            float hh = h[orow * 64 + colx];
            out[outbase + orow * 64 + colx] = 0.5f * u + 0.5f * hh;
        }
    }
}

// ---------------------------------------------------------------------------
__global__ void xnew_kernel(
    const float* __restrict__ coordsA, const float* __restrict__ origcA,
    const float* __restrict__ coordsB, const float* __restrict__ origcB,
    const float* __restrict__ xupA, const float* __restrict__ xupB,
    const int* __restrict__ rowptrA, const int* __restrict__ rowptrB,
    float* __restrict__ out)
{
    int i = blockIdx.x * 256 + threadIdx.x;   // 49152 total
    int br = (i >= 24576) ? 1 : 0;
    int j = i - br * 24576;
    const float* coords = br ? coordsB : coordsA;
    const float* origc = br ? origcB : origcA;
    const float* xup = br ? xupB : xupA;
    const int* rp = br ? rowptrB : rowptrA;
    int node = j / 3;
    float cnt = (float)(rp[node + 1] - rp[node]);
    float val = 0.25f * origc[j] + 0.75f * coords[j] + xup[j] / fmaxf(cnt, 1.0f);
    out[(br ? 548864 : 0) + j] = val;
}

// ---------------------------------------------------------------------------
extern "C" void kernel_launch(void* const* d_in, const int* in_sizes, int n_in,
                              void* d_out, int out_size, void* d_ws, size_t ws_size,
                              hipStream_t stream)
{
    int base = n_in - 29;
    for (int i = 0; i < n_in; i++) {
        if (in_sizes[i] == 11200) { base = i; break; }
    }
    const float* coordsA = (const float*)d_in[0];
    const float* hA      = (const float*)d_in[1];
    const float* origA   = (const float*)d_in[2];
    const float* origcA  = (const float*)d_in[3];
    const float* efA     = (const float*)d_in[4];
    const float* coordsB = (const float*)d_in[5];
    const float* hB      = (const float*)d_in[6];
    const float* origB   = (const float*)d_in[7];
    const float* origcB  = (const float*)d_in[8];
    const float* efB     = (const float*)d_in[9];
    const float* P[25];
    for (int k = 0; k < 25; k++) P[k] = (const float*)d_in[base + k];
    const int* srcA = (const int*)d_in[base + 25];
    const int* dstA = (const int*)d_in[base + 26];
    const int* srcB = (const int*)d_in[base + 27];
    const int* dstB = (const int*)d_in[base + 28];

    char* ws = (char*)d_ws;
    unsigned short* msgbufA = (unsigned short*)(ws + 0);          // 33.5 MB
    unsigned short* msgbufB = (unsigned short*)(ws + 33554432);   // 33.5 MB
    float* Opart  = (float*)(ws + 0);                             // 16 MB (reuse after gather)
    float* mlbuf  = (float*)(ws + 16777216);                      // 512 KB (reuse)
    unsigned short* hbA  = (unsigned short*)(ws + 67108864);      // 1 MB
    unsigned short* hbB  = (unsigned short*)(ws + 68157440);
    unsigned short* efbA = (unsigned short*)(ws + 69206016);      // 16 MB
    unsigned short* efbB = (unsigned short*)(ws + 85983232);
    float* aggrA  = (float*)(ws + 102760448);                     // 2 MB
    float* aggrB  = (float*)(ws + 104857600);
    unsigned short* qbuf = (unsigned short*)(ws + 106954752);     // 1 MB
    unsigned short* kbuf = (unsigned short*)(ws + 108003328);
    unsigned short* vTb  = (unsigned short*)(ws + 109051904);
    unsigned short* attb = (unsigned short*)(ws + 110100480);
    // zero region (one memset, 327,680 B): xupA,xupB,histA,histB,curA,curB
    float* xupA = (float*)(ws + 111149056);
    float* xupB = (float*)(ws + 111247360);
    int* histA  = (int*)(ws + 111345664);
    int* histB  = (int*)(ws + 111378432);
    int* curA   = (int*)(ws + 111411200);
    int* curB   = (int*)(ws + 111443968);
    int* rowptrA = (int*)(ws + 111476736);
    int* rowptrB = (int*)(ws + 111517696);
    int* posA   = (int*)(ws + 111558656);                          // 1 MB
    int* posB   = (int*)(ws + 112607232);                          // 1 MB
    float* out = (float*)d_out;

    hipMemsetAsync(ws + 111149056, 0, 327680, stream);

    prep_kernel<<<17408, 256, 0, stream>>>(hA, hB, efA, efB, hbA, hbB, efbA, efbB);

    hist_kernel<<<1024, 256, 0, stream>>>(dstA, dstB, histA, histB);
    scan_kernel<<<2, 1024, 0, stream>>>(histA, histB, rowptrA, rowptrB);
    scatter_kernel<<<1024, 256, 0, stream>>>(dstA, dstB, rowptrA, rowptrB,
                                             curA, curB, posA, posB);

    edge_kernel<<<1024, 512, 0, stream>>>(
        coordsA, hbA, efbA, srcA, dstA, posA,
        coordsB, hbB, efbB, srcB, dstB, posB,
        P[0], P[1], P[2], P[3], P[4], P[5], P[6], P[7],
        P[19], P[20], P[21], P[22], P[23], P[24],
        msgbufA, msgbufB, xupA, xupB);

    gather_kernel<<<2048, 256, 0, stream>>>(rowptrA, rowptrB, msgbufA, msgbufB,
                                            aggrA, aggrB);

    qkv_kernel<<<128, 256, 0, stream>>>(hbA, hbB, P[8], P[9], P[10], qbuf, kbuf, vTb);

    attn_kernel<<<1024, 256, 0, stream>>>(qbuf, kbuf, vTb, Opart, mlbuf);
    combine_kernel<<<2048, 256, 0, stream>>>(Opart, mlbuf, attb);

    node_kernel<<<256, 256, 0, stream>>>(
        hA, hB, origA, origB, attb, aggrA, aggrB,
        P[11], P[12], P[13], P[14], P[15], P[16], P[17], P[18], out);

    xnew_kernel<<<192, 256, 0, stream>>>(
        coordsA, origcA, coordsB, origcB, xupA, xupB, rowptrA, rowptrB, out);
}

// Round 8
// 757.736 us; speedup vs baseline: 1.3091x; 1.0075x over previous
//
#include <hip/hip_runtime.h>
#include <cstdint>
#include <cstddef>

// ---------------------------------------------------------------------------
// Fine_Grain_Layer. f32 I/O, bf16 MFMA operands, f32 accumulate.
// R15 -> R16: transposed softmax in attn_kernel (the proven edge operand-
// swap pattern, applied where it is register-NEGATIVE): QK^T computed as
// MFMA16(k_frag, qf) -> lane (l15,g) holds S[qrow l15][k=16t+4g+r]; softmax
// max/sum are in-lane trees + 2 shfl_xor(16/32) each (was 32 shuffles in
// 4-deep rowmax16/rowsum16 chains per kt); m_/l_ become per-lane scalars
// (-6 regs); P written as 4x b64 to pbuf in the SAME swizzled layout the
// pf reads already use (byte-identical to edge msgb, functionally proven);
// oacc rescale fetches per-row sc via 4 bpermute shuffles. PV, oacc layout,
// Opart writes unchanged. No param vectors exist in attn -> the R14 LICM-
// hoist spill mechanism cannot apply. Edge kernel untouched (R13/R15 body,
// pinned at ~165us by the 128-reg cliff).
// ~162 us of dur is the harness's 1 GiB ws poison fill; several hundred
// more us are the harness reset()'s restore dispatches (uncontrollable).
// ---------------------------------------------------------------------------

typedef short bf16x8 __attribute__((ext_vector_type(8)));
typedef float floatx4 __attribute__((ext_vector_type(4)));

#define MFMA16(a, b, c) __builtin_amdgcn_mfma_f32_16x16x32_bf16((a), (b), (c), 0, 0, 0)

__device__ __forceinline__ unsigned short f2bf(float f) {
    unsigned int u = __builtin_bit_cast(unsigned int, f);
    u += 0x7fffu + ((u >> 16) & 1u);   // round to nearest even
    return (unsigned short)(u >> 16);
}
__device__ __forceinline__ float bf2f(unsigned short u) {
    unsigned int x = ((unsigned int)u) << 16;
    return __builtin_bit_cast(float, x);
}
__device__ __forceinline__ bf16x8 cvt8v(const float* __restrict__ p) {
    float4 a = *(const float4*)p;
    float4 b = *(const float4*)(p + 4);
    bf16x8 r;
    r[0] = (short)f2bf(a.x); r[1] = (short)f2bf(a.y);
    r[2] = (short)f2bf(a.z); r[3] = (short)f2bf(a.w);
    r[4] = (short)f2bf(b.x); r[5] = (short)f2bf(b.y);
    r[6] = (short)f2bf(b.z); r[7] = (short)f2bf(b.w);
    return r;
}
__device__ __forceinline__ float rowsum16(float x) {
    x += __shfl_xor(x, 1);
    x += __shfl_xor(x, 2);
    x += __shfl_xor(x, 4);
    x += __shfl_xor(x, 8);
    return x;
}
__device__ __forceinline__ float lrelu(float x) { return x > 0.f ? x : 0.01f * x; }
__device__ __forceinline__ float ln_rstd(float s2, float mean) {
    float var = s2 * 0.015625f - mean * mean;
    return rsqrtf(fmaxf(var, 0.0f) + 1e-5f);
}

__constant__ float INVSIG[16] = {
    1.0f, 0.6666666865f, 0.4444444597f, 0.2962962985f, 0.1975308657f,
    0.1316872428f, 0.0877914950f, 0.0585276633f, 0.0390184447f, 0.0260122959f,
    0.0173415299f, 0.0115610203f, 0.0077073467f, 0.0051382311f, 0.0034254875f, 0.0f};

// ---------------------------------------------------------------------------
// Pre-convert h (2x524288) and ef (2x8388608) to bf16. Quad-granular.
__global__ void prep_kernel(const float* __restrict__ hA, const float* __restrict__ hB,
                            const float* __restrict__ efA, const float* __restrict__ efB,
                            unsigned short* __restrict__ hbA, unsigned short* __restrict__ hbB,
                            unsigned short* __restrict__ efbA, unsigned short* __restrict__ efbB)
{
    int q = blockIdx.x * 256 + threadIdx.x;   // 4,456,448 quads exactly
    const float* s; unsigned short* d; int off;
    if (q < 131072)        { s = hA;  d = hbA;  off = q; }
    else if (q < 262144)   { s = hB;  d = hbB;  off = q - 131072; }
    else if (q < 2359296)  { s = efA; d = efbA; off = q - 262144; }
    else                   { s = efB; d = efbB; off = q - 2359296; }
    float4 v = *(const float4*)(s + (size_t)off * 4);
    ushort4 o;
    o.x = f2bf(v.x); o.y = f2bf(v.y); o.z = f2bf(v.z); o.w = f2bf(v.w);
    *(ushort4*)(d + (size_t)off * 4) = o;
}

// ---------------------------------------------------------------------------
__global__ void hist_kernel(const int* __restrict__ dstA, const int* __restrict__ dstB,
                            int* __restrict__ histA, int* __restrict__ histB)
{
    int e = blockIdx.x * 256 + threadIdx.x;   // exactly 262144
    atomicAdd(&histA[dstA[e]], 1);
    atomicAdd(&histB[dstB[e]], 1);
}

__global__ void scan_kernel(const int* __restrict__ histA, const int* __restrict__ histB,
                            int* __restrict__ rowptrA, int* __restrict__ rowptrB)
{
    const int b = blockIdx.x;   // 0 = A, 1 = B
    const int* hist = b ? histB : histA;
    int* rowptr = b ? rowptrB : rowptrA;
    __shared__ int part[1024];
    int t = threadIdx.x;
    int v[8]; int s = 0;
    #pragma unroll
    for (int j = 0; j < 8; j++) { v[j] = hist[t * 8 + j]; s += v[j]; }
    part[t] = s;
    __syncthreads();
    for (int off = 1; off < 1024; off <<= 1) {
        int x = part[t];
        int y = (t >= off) ? part[t - off] : 0;
        __syncthreads();
        part[t] = x + y;
        __syncthreads();
    }
    int run = (t > 0) ? part[t - 1] : 0;
    #pragma unroll
    for (int j = 0; j < 8; j++) { rowptr[t * 8 + j] = run; run += v[j]; }
    if (t == 1023) rowptr[8192] = run;
}

// pos[e] = slot of edge e in dst-CSR order
__global__ void scatter_kernel(const int* __restrict__ dstA, const int* __restrict__ dstB,
                               const int* __restrict__ rowptrA, const int* __restrict__ rowptrB,
                               int* __restrict__ curA, int* __restrict__ curB,
                               int* __restrict__ posA, int* __restrict__ posB)
{
    int e = blockIdx.x * 256 + threadIdx.x;   // exactly 262144
    int dA = dstA[e];
    posA[e] = rowptrA[dA] + atomicAdd(&curA[dA], 1);
    int dB = dstB[e];
    posB[e] = rowptrB[dB] + atomicAdd(&curB[dB], 1);
}

// ---------------------------------------------------------------------------
// Edge kernel, both branches: one wave = 16 edges; 8 waves/block; barrier-free
// body. bf16 inputs; msg rows written at CSR slot pos[e].
// Minimal prefetch: next iter's idx (3 ints) + ef (1 bf16x8) only.
// LN1/LN2 row-form (register-cheap); coef MLP transposed-C (register-neutral).
__global__ __launch_bounds__(512, 2) void edge_kernel(
    const float* __restrict__ coordsA, const unsigned short* __restrict__ hbA,
    const unsigned short* __restrict__ efbA, const int* __restrict__ srcA,
    const int* __restrict__ dstA, const int* __restrict__ posA,
    const float* __restrict__ coordsB, const unsigned short* __restrict__ hbB,
    const unsigned short* __restrict__ efbB, const int* __restrict__ srcB,
    const int* __restrict__ dstB, const int* __restrict__ posB,
    const float* __restrict__ eW1, const float* __restrict__ eb1,
    const float* __restrict__ eg1, const float* __restrict__ ebt1,
    const float* __restrict__ eW2, const float* __restrict__ eb2,
    const float* __restrict__ eg2, const float* __restrict__ ebt2,
    const float* __restrict__ cW1, const float* __restrict__ cb1,
    const float* __restrict__ cg1, const float* __restrict__ cbt1,
    const float* __restrict__ cW2, const float* __restrict__ cb2,
    unsigned short* __restrict__ msgbufA, unsigned short* __restrict__ msgbufB,
    float* __restrict__ xupA, float* __restrict__ xupB)
{
    // XOR-swizzled LDS tiles: addr = row*stride + ((blk ^ (row&7))<<3) + (col&7)
    __shared__ __attribute__((aligned(16))) short Wt1[64 * 192];   // 24576 B
    __shared__ __attribute__((aligned(16))) short Wt2s[64 * 64];   //  8192 B
    __shared__ __attribute__((aligned(16))) short Wc1s[64 * 64];   //  8192 B
    __shared__ __attribute__((aligned(16))) float pb[644];         //  2576 B
    __shared__ __attribute__((aligned(16))) short msgb[8][16 * 64];// 16384 B -> 59920 total

    const int tid = threadIdx.x;

    for (int i = tid; i < 64 * 192; i += 512) {
        int n = i / 192, kk = i - n * 192;
        float w = (kk < 175) ? eW1[kk * 64 + n] : 0.0f;
        Wt1[n * 192 + ((((kk >> 3) ^ (n & 7)) << 3) | (kk & 7))] = (short)f2bf(w);
    }
    for (int i = tid; i < 4096; i += 512) {
        int n = i >> 6, kk = i & 63;
        int o = n * 64 + ((((kk >> 3) ^ (n & 7)) << 3) | (kk & 7));
        Wt2s[o] = (short)f2bf(eW2[kk * 64 + n]);
        Wc1s[o] = (short)f2bf(cW1[kk * 64 + n]);
    }
    if (tid < 64) {
        pb[tid]       = eb1[tid];
        pb[64 + tid]  = eg1[tid];
        pb[128 + tid] = ebt1[tid];
        pb[192 + tid] = eb2[tid];
        pb[256 + tid] = eg2[tid];
        pb[320 + tid] = ebt2[tid];
        pb[384 + tid] = cb1[tid];
        pb[448 + tid] = cg1[tid];
        pb[512 + tid] = cbt1[tid];
        pb[576 + tid] = cW2[tid];
    }
    if (tid == 0) pb[640] = cb2[0];
    __syncthreads();   // the ONLY barrier

    const int wave = tid >> 6;
    const int lane = tid & 63;
    const int l15 = lane & 15;
    const int g = lane >> 4;
    const int x7 = l15 & 7;
    const int gi0 = blockIdx.x * 8 + wave;   // < 8192

    // iteration it (0..3): branch = it>>1; in-branch edge base alternates
    // between eA0 (it 0,2) and eA1 (it 1,3).
    const int eA0 = (gi0 & 16383) * 16 + l15;
    const int eA1 = eA0 + 8192 * 16;

    // prefetch it=0 (branch A, edge eA0)
    int s_n  = srcA[eA0];
    int d_n  = dstA[eA0];
    int sl_n = posA[eA0];
    bf16x8 ef_n = *(const bf16x8*)(efbA + (size_t)eA0 * 32 + 8 * g);

    #pragma unroll 1
    for (int it = 0; it < 4; ++it) {
        const int br = it >> 1;
        const float* coords = br ? coordsB : coordsA;
        const unsigned short* hb = br ? hbB : hbA;
        unsigned short* msgbuf = br ? msgbufB : msgbufA;
        float* xup = br ? xupB : xupA;

        const int s = s_n, d0 = d_n, slot = sl_n;
        const bf16x8 ef = ef_n;

        // current-iteration dependent loads: issue ASAP
        bf16x8 h0 = *(const bf16x8*)(hb + (size_t)s * 64 + 8 * g);
        bf16x8 h1 = *(const bf16x8*)(hb + (size_t)s * 64 + 32 + 8 * g);
        bf16x8 h2 = *(const bf16x8*)(hb + (size_t)d0 * 64 + 8 * g);
        bf16x8 h3 = *(const bf16x8*)(hb + (size_t)d0 * 64 + 32 + 8 * g);
        float cs0 = coords[s * 3 + 0];
        float cs1 = coords[s * 3 + 1];
        float cs2 = coords[s * 3 + 2];
        float cd0 = coords[d0 * 3 + 0];
        float cd1 = coords[d0 * 3 + 1];
        float cd2 = coords[d0 * 3 + 2];

        // prefetch next iteration's idx + ef (addresses independent of above)
        if (it < 3) {
            const int brn = (it + 1) >> 1;
            const int en = (it & 1) ? eA0 : eA1;
            const int* srcN = brn ? srcB : srcA;
            const int* dstN = brn ? dstB : dstA;
            const int* posN = brn ? posB : posA;
            const unsigned short* efbN = brn ? efbB : efbA;
            s_n  = srcN[en];
            d_n  = dstN[en];
            sl_n = posN[en];
            ef_n = *(const bf16x8*)(efbN + (size_t)en * 32 + 8 * g);
        }

        const float xr0 = cs0 - cd0;
        const float xr1 = cs1 - cd1;
        const float xr2 = cs2 - cd2;
        const float d2 = xr0 * xr0 + xr1 * xr1 + xr2 * xr2;

        bf16x8 af5;
        #pragma unroll
        for (int j = 0; j < 8; j++) {
            int idx = 8 * g + j;
            float rv = 0.0f;
            if (g < 2 && idx < 15) rv = __expf(-d2 * INVSIG[idx & 15]);
            af5[j] = (short)f2bf(rv);
        }

        // layer 1: [16 x 192] @ [192 x 64]
        floatx4 acc1[4];
        #pragma unroll
        for (int t = 0; t < 4; t++) acc1[t] = (floatx4)0.0f;
        {
            bf16x8 af[6] = {h0, h1, h2, h3, ef, af5};
            #pragma unroll
            for (int c = 0; c < 6; c++) {
                #pragma unroll
                for (int t = 0; t < 4; t++) {
                    bf16x8 b = *(const bf16x8*)(&Wt1[(t * 16 + l15) * 192 + ((((c << 2) | g) ^ x7) << 3)]);
                    acc1[t] = MFMA16(af[c], b, acc1[t]);
                }
            }
        }

        float vv[4][4];
        #pragma unroll
        for (int t = 0; t < 4; t++)
            #pragma unroll
            for (int r = 0; r < 4; r++) vv[t][r] = acc1[t][r] + pb[t * 16 + l15];
        #pragma unroll
        for (int r = 0; r < 4; r++) {
            float s1 = vv[0][r] + vv[1][r] + vv[2][r] + vv[3][r];
            float s2 = vv[0][r] * vv[0][r] + vv[1][r] * vv[1][r] + vv[2][r] * vv[2][r] + vv[3][r] * vv[3][r];
            s1 = rowsum16(s1);
            s2 = rowsum16(s2);
            float mean = s1 * 0.015625f;
            float rstd = ln_rstd(s2, mean);
            int row = 4 * g + r;
            int rbase = row * 64;
            int r7 = row & 7;
            #pragma unroll
            for (int t = 0; t < 4; t++) {
                int colx = t * 16 + l15;
                float x = (vv[t][r] - mean) * rstd * pb[64 + colx] + pb[128 + colx];
                x = lrelu(x);
                msgb[wave][rbase + (((((t << 1) | (l15 >> 3)) ^ r7) << 3) | x7)] = (short)f2bf(x);
            }
        }

        // layer 2: [16 x 64] @ [64 x 64] -> msg (LN, no lrelu)
        bf16x8 a2[2];
        a2[0] = *(const bf16x8*)(&msgb[wave][l15 * 64 + (((g) ^ x7) << 3)]);
        a2[1] = *(const bf16x8*)(&msgb[wave][l15 * 64 + (((4 | g) ^ x7) << 3)]);
        floatx4 acc2[4];
        #pragma unroll
        for (int t = 0; t < 4; t++) acc2[t] = (floatx4)0.0f;
        #pragma unroll
        for (int c = 0; c < 2; c++) {
            #pragma unroll
            for (int t = 0; t < 4; t++) {
                bf16x8 b = *(const bf16x8*)(&Wt2s[(t * 16 + l15) * 64 + ((((c << 2) | g) ^ x7) << 3)]);
                acc2[t] = MFMA16(a2[c], b, acc2[t]);
            }
        }
        float vm[4][4];
        #pragma unroll
        for (int t = 0; t < 4; t++)
            #pragma unroll
            for (int r = 0; r < 4; r++) vm[t][r] = acc2[t][r] + pb[192 + t * 16 + l15];
        #pragma unroll
        for (int r = 0; r < 4; r++) {
            float s1 = vm[0][r] + vm[1][r] + vm[2][r] + vm[3][r];
            float s2 = vm[0][r] * vm[0][r] + vm[1][r] * vm[1][r] + vm[2][r] * vm[2][r] + vm[3][r] * vm[3][r];
            s1 = rowsum16(s1);
            s2 = rowsum16(s2);
            float mean = s1 * 0.015625f;
            float rstd = ln_rstd(s2, mean);
            #pragma unroll
            for (int t = 0; t < 4; t++) {
                int colx = t * 16 + l15;
                vm[t][r] = (vm[t][r] - mean) * rstd * pb[256 + colx] + pb[320 + colx];
            }
        }
        #pragma unroll
        for (int r = 0; r < 4; r++) {
            int row = 4 * g + r;
            int rbase = row * 64;
            int r7 = row & 7;
            #pragma unroll
            for (int t = 0; t < 4; t++)
                msgb[wave][rbase + (((((t << 1) | (l15 >> 3)) ^ r7) << 3) | x7)] = (short)f2bf(vm[t][r]);
        }

        // single re-read of final msg fragments: reused for the global store
        // AND as the coef-MLP B-operand (transposed MFMA).
        bf16x8 m0 = *(const bf16x8*)(&msgb[wave][l15 * 64 + (((g) ^ x7) << 3)]);
        bf16x8 m1 = *(const bf16x8*)(&msgb[wave][l15 * 64 + (((4 | g) ^ x7) << 3)]);
        {
            unsigned short* mrow = msgbuf + (size_t)slot * 64;
            *(bf16x8*)(mrow + 8 * g)      = m0;
            *(bf16x8*)(mrow + 32 + 8 * g) = m1;
        }

        // coef MLP, TRANSPOSED-C: W-frag as A-operand, msg-frag as B-operand.
        // acc3[t][r] = coef-layer feature (16t+4g+r) of edge l15. LN stats
        // reduce across g-groups (shfl_xor 16/32); cW2 dot in-lane; every
        // lane ends holding coef of its own edge l15 (no redistribute).
        floatx4 acc3[4];
        #pragma unroll
        for (int t = 0; t < 4; t++) acc3[t] = (floatx4)0.0f;
        #pragma unroll
        for (int c = 0; c < 2; c++) {
            #pragma unroll
            for (int t = 0; t < 4; t++) {
                bf16x8 b = *(const bf16x8*)(&Wc1s[(t * 16 + l15) * 64 + ((((c << 2) | g) ^ x7) << 3)]);
                acc3[t] = MFMA16(b, c == 0 ? m0 : m1, acc3[t]);
            }
        }
        float cf;
        {
            float s1 = 0.f, s2 = 0.f;
            #pragma unroll
            for (int t = 0; t < 4; t++) {
                const floatx4 bv = *(const floatx4*)&pb[384 + t * 16 + 4 * g];
                #pragma unroll
                for (int r = 0; r < 4; r++) {
                    float x = acc3[t][r] + bv[r];
                    acc3[t][r] = x;
                    s1 += x; s2 += x * x;
                }
            }
            s1 += __shfl_xor(s1, 16); s1 += __shfl_xor(s1, 32);
            s2 += __shfl_xor(s2, 16); s2 += __shfl_xor(s2, 32);
            const float mean = s1 * 0.015625f;
            const float rstd = ln_rstd(s2, mean);
            float p = 0.f;
            #pragma unroll
            for (int t = 0; t < 4; t++) {
                const floatx4 gv = *(const floatx4*)&pb[448 + t * 16 + 4 * g];
                const floatx4 bt = *(const floatx4*)&pb[512 + t * 16 + 4 * g];
                const floatx4 wv = *(const floatx4*)&pb[576 + t * 16 + 4 * g];
                #pragma unroll
                for (int r = 0; r < 4; r++) {
                    float x = (acc3[t][r] - mean) * rstd * gv[r] + bt[r];
                    p += lrelu(x) * wv[r];
                }
            }
            p += __shfl_xor(p, 16); p += __shfl_xor(p, 32);
            cf = p + pb[640];       // every lane: coef of its edge l15
        }

        if (g < 3) {
            float xrg = (g == 0) ? xr0 : (g == 1) ? xr1 : xr2;
            atomicAdd(&xup[(size_t)d0 * 3 + g], xrg * cf);
        }
    }
}

// ---------------------------------------------------------------------------
// Gather-reduce over CSR-ordered msgbuf: contiguous streaming reads.
__global__ __launch_bounds__(256, 4) void gather_kernel(
    const int* __restrict__ rowptrA, const int* __restrict__ rowptrB,
    const unsigned short* __restrict__ msgbufA, const unsigned short* __restrict__ msgbufB,
    float* __restrict__ aggrA, float* __restrict__ aggrB)
{
    const int tid = threadIdx.x;
    const int wave = tid >> 6, lane = tid & 63;
    const int nwaves = gridDim.x * 4;
    for (int u = blockIdx.x * 4 + wave; u < 16384; u += nwaves) {
        const int br = u >> 13;
        const int n = u & 8191;
        const int* rowptr = br ? rowptrB : rowptrA;
        const unsigned short* mb = br ? msgbufB : msgbufA;
        float* aggr = br ? aggrB : aggrA;
        int base = rowptr[n];
        int deg = rowptr[n + 1] - base;
        float a[8];
        #pragma unroll
        for (int j = 0; j < 8; j++) a[j] = 0.f;
        int i = 0;
        for (; i + 8 <= deg; i += 8) {
            #pragma unroll
            for (int j = 0; j < 8; j++)
                a[j] += bf2f(mb[(size_t)(base + i + j) * 64 + lane]);
        }
        for (; i < deg; i++) a[0] += bf2f(mb[(size_t)(base + i) * 64 + lane]);
        float t = (a[0] + a[1]) + (a[2] + a[3]) + ((a[4] + a[5]) + (a[6] + a[7]));
        aggr[(size_t)n * 64 + lane] = t / fmaxf((float)deg, 1.0f);
    }
}

// ---------------------------------------------------------------------------
__global__ __launch_bounds__(256, 2) void qkv_kernel(
    const unsigned short* __restrict__ hbA, const unsigned short* __restrict__ hbB,
    const float* __restrict__ qW, const float* __restrict__ kW,
    const float* __restrict__ vW,
    unsigned short* __restrict__ qo, unsigned short* __restrict__ ko,
    unsigned short* __restrict__ vTo)
{
    __shared__ __attribute__((aligned(16))) short Wq[64 * 64];
    __shared__ __attribute__((aligned(16))) short Wk[64 * 64];
    __shared__ __attribute__((aligned(16))) short Wv[64 * 64];
    const int tid = threadIdx.x;
    for (int i = tid; i < 4096; i += 256) {
        int n = i >> 6, kk = i & 63;
        int o = n * 64 + ((((kk >> 3) ^ (n & 7)) << 3) | (kk & 7));
        Wq[o] = (short)f2bf(qW[kk * 64 + n]);
        Wk[o] = (short)f2bf(kW[kk * 64 + n]);
        Wv[o] = (short)f2bf(vW[kk * 64 + n]);
    }
    __syncthreads();
    const int wave = tid >> 6, lane = tid & 63, l15 = lane & 15, g = lane >> 4;
    const int x7 = l15 & 7;
    const int row0 = blockIdx.x * 64 + wave * 16;
    bf16x8 aA[2], aB[2];
    aA[0] = *(const bf16x8*)(hbA + (size_t)(row0 + l15) * 64 + 8 * g);
    aA[1] = *(const bf16x8*)(hbA + (size_t)(row0 + l15) * 64 + 32 + 8 * g);
    aB[0] = *(const bf16x8*)(hbB + (size_t)(row0 + l15) * 64 + 8 * g);
    aB[1] = *(const bf16x8*)(hbB + (size_t)(row0 + l15) * 64 + 32 + 8 * g);
    floatx4 aq[4], ak4[4], av[4];
    #pragma unroll
    for (int t = 0; t < 4; t++) { aq[t] = (floatx4)0.0f; ak4[t] = (floatx4)0.0f; av[t] = (floatx4)0.0f; }
    #pragma unroll
    for (int c = 0; c < 2; c++) {
        #pragma unroll
        for (int t = 0; t < 4; t++) {
            int wo = (t * 16 + l15) * 64 + ((((c << 2) | g) ^ x7) << 3);
            aq[t] = MFMA16(aA[c], *(const bf16x8*)(&Wq[wo]), aq[t]);
            ak4[t] = MFMA16(aB[c], *(const bf16x8*)(&Wk[wo]), ak4[t]);
            av[t] = MFMA16(aB[c], *(const bf16x8*)(&Wv[wo]), av[t]);
        }
    }
    #pragma unroll
    for (int t = 0; t < 4; t++) {
        #pragma unroll
        for (int r = 0; r < 4; r++) {
            int orow = row0 + 4 * g + r, ocol = t * 16 + l15;
            qo[(size_t)orow * 64 + ocol] = f2bf(lrelu(aq[t][r]));
            ko[(size_t)orow * 64 + ocol] = f2bf(lrelu(ak4[t][r]));
            vTo[(size_t)ocol * 8192 + orow] = f2bf(av[t][r]);   // v transposed
        }
    }
}

// ---------------------------------------------------------------------------
// Flash attention, K-split=8, direct L2 b-frag loads, no barriers.
// TRANSPOSED softmax: QK^T as MFMA16(k_frag, qf) -> lane (l15,g) holds
// S[qrow l15][k = 16t+4g+r]; max/sum in-lane + 2 shfl_xor(16/32); m_/l_
// per-lane scalars; P written b64 in the edge-proven swizzled layout; pf
// reads and PV unchanged; oacc rescale via 4 per-row sc broadcasts.
__global__ __launch_bounds__(256, 4) void attn_kernel(
    const unsigned short* __restrict__ qb_, const unsigned short* __restrict__ kb_,
    const unsigned short* __restrict__ vT,
    float* __restrict__ Opart, float* __restrict__ ml)
{
    __shared__ __attribute__((aligned(16))) short pbuf[4][16 * 64];
    const int tid = threadIdx.x;
    const int wave = tid >> 6, lane = tid & 63, l15 = lane & 15, g = lane >> 4;
    const int x7 = l15 & 7;
    const int g2 = 4 * (g & 1);
    const int gh = g >> 1;
    const int qblock = blockIdx.x >> 3;         // 128 q-blocks
    const int split = blockIdx.x & 7;           // 8 k-splits
    const int qrow0 = qblock * 64 + wave * 16;
    const int kbase = split * 1024;
    bf16x8 qf[2];
    qf[0] = *(const bf16x8*)(qb_ + (size_t)(qrow0 + l15) * 64 + 8 * g);
    qf[1] = *(const bf16x8*)(qb_ + (size_t)(qrow0 + l15) * 64 + 32 + 8 * g);
    float m_ = -1.0e30f, l_ = 0.f;     // running stats of q-row (qrow0+l15)
    floatx4 oacc[4];
    #pragma unroll
    for (int t = 0; t < 4; t++) oacc[t] = (floatx4)0.0f;

    for (int kt = 0; kt < 16; kt++) {
        const int krow0 = kbase + kt * 64;
        floatx4 sacc[4];
        #pragma unroll
        for (int t = 0; t < 4; t++) sacc[t] = (floatx4)0.0f;
        #pragma unroll
        for (int c = 0; c < 2; c++) {
            #pragma unroll
            for (int t = 0; t < 4; t++) {
                bf16x8 b = *(const bf16x8*)(kb_ + (size_t)(krow0 + t * 16 + l15) * 64 + 32 * c + 8 * g);
                sacc[t] = MFMA16(b, qf[c], sacc[t]);   // transposed: lane = q-row
            }
        }
        // sacc[t][r] = S[qrow l15][k-local 16t+4g+r]; in-lane tree max
        float mx;
        {
            float m0 = fmaxf(fmaxf(sacc[0][0], sacc[0][1]), fmaxf(sacc[0][2], sacc[0][3]));
            float m1 = fmaxf(fmaxf(sacc[1][0], sacc[1][1]), fmaxf(sacc[1][2], sacc[1][3]));
            float m2 = fmaxf(fmaxf(sacc[2][0], sacc[2][1]), fmaxf(sacc[2][2], sacc[2][3]));
            float m3 = fmaxf(fmaxf(sacc[3][0], sacc[3][1]), fmaxf(sacc[3][2], sacc[3][3]));
            mx = fmaxf(fmaxf(m0, m1), fmaxf(m2, m3));
        }
        mx = fmaxf(mx, __shfl_xor(mx, 16));
        mx = fmaxf(mx, __shfl_xor(mx, 32));
        const float mn = fmaxf(m_, mx);
        const float sc = __expf(fminf(m_ - mn, 0.f));
        float ps = 0.f;
        #pragma unroll
        for (int t = 0; t < 4; t++) {
            float p0 = __expf(fminf(sacc[t][0] - mn, 0.f));
            float p1 = __expf(fminf(sacc[t][1] - mn, 0.f));
            float p2 = __expf(fminf(sacc[t][2] - mn, 0.f));
            float p3 = __expf(fminf(sacc[t][3] - mn, 0.f));
            ps += (p0 + p1) + (p2 + p3);
            uint2 pk;
            pk.x = (unsigned int)f2bf(p0) | ((unsigned int)f2bf(p1) << 16);
            pk.y = (unsigned int)f2bf(p2) | ((unsigned int)f2bf(p3) << 16);
            const int blk = (2 * t + gh) ^ x7;
            *(uint2*)&pbuf[wave][l15 * 64 + (blk << 3) + g2] = pk;
        }
        ps += __shfl_xor(ps, 16);
        ps += __shfl_xor(ps, 32);
        l_ = l_ * sc + ps;
        m_ = mn;
        // rescale oacc: row 4g+r needs sc of that q-row (lives in lane 4g+r)
        #pragma unroll
        for (int r = 0; r < 4; r++) {
            float scr = __shfl(sc, 4 * g + r);
            #pragma unroll
            for (int t = 0; t < 4; t++) oacc[t][r] *= scr;
        }
        bf16x8 pf[2];
        pf[0] = *(const bf16x8*)(&pbuf[wave][l15 * 64 + (((g) ^ x7) << 3)]);
        pf[1] = *(const bf16x8*)(&pbuf[wave][l15 * 64 + (((4 | g) ^ x7) << 3)]);
        #pragma unroll
        for (int c = 0; c < 2; c++) {
            #pragma unroll
            for (int t = 0; t < 4; t++) {
                bf16x8 b = *(const bf16x8*)(vT + (size_t)(t * 16 + l15) * 8192 + krow0 + 32 * c + 8 * g);
                oacc[t] = MFMA16(pf[c], b, oacc[t]);
            }
        }
    }
    #pragma unroll
    for (int t = 0; t < 4; t++) {
        #pragma unroll
        for (int r = 0; r < 4; r++) {
            int row = qrow0 + 4 * g + r;
            Opart[((size_t)split * 8192 + row) * 64 + t * 16 + l15] = oacc[t][r];
        }
    }
    if (g == 0) {
        int row = qrow0 + l15;
        ml[((size_t)split * 8192 + row) * 2 + 0] = m_;
        ml[((size_t)split * 8192 + row) * 2 + 1] = l_;
    }
}

__global__ void combine_kernel(const float* __restrict__ Opart, const float* __restrict__ ml,
                               unsigned short* __restrict__ attb)
{
    int idx = blockIdx.x * 256 + threadIdx.x;   // 8192*64
    int row = idx >> 6, col = idx & 63;
    float mm = -1.0e30f;
    #pragma unroll
    for (int s = 0; s < 8; s++) mm = fmaxf(mm, ml[((size_t)s * 8192 + row) * 2]);
    float l = 0.f, o = 0.f;
    #pragma unroll
    for (int s = 0; s < 8; s++) {
        float w = __expf(ml[((size_t)s * 8192 + row) * 2] - mm);
        l += w * ml[((size_t)s * 8192 + row) * 2 + 1];
        o += w * Opart[((size_t)s * 8192 + row) * 64 + col];
    }
    attb[(size_t)row * 64 + col] = f2bf(o / l);
}

// ---------------------------------------------------------------------------
__global__ __launch_bounds__(256, 2) void node_kernel(
    const float* __restrict__ hA, const float* __restrict__ hB,
    const float* __restrict__ origA, const float* __restrict__ origB,
    const unsigned short* __restrict__ attb,
    const float* __restrict__ aggrA, const float* __restrict__ aggrB,
    const float* __restrict__ nW1, const float* __restrict__ nb1,
    const float* __restrict__ ng1, const float* __restrict__ nbt1,
    const float* __restrict__ nW2, const float* __restrict__ nb2,
    const float* __restrict__ ng2, const float* __restrict__ nbt2,
    float* __restrict__ out)
{
    __shared__ __attribute__((aligned(16))) short W1t[64 * 256];
    __shared__ __attribute__((aligned(16))) short W2t[64 * 64];
    __shared__ __attribute__((aligned(16))) float pb[6 * 64];
    __shared__ __attribute__((aligned(16))) short ubuf[4][16 * 64];
    const int tid = threadIdx.x;
    for (int i = tid; i < 64 * 256; i += 256) {
        int n = i >> 8, kk = i & 255;
        W1t[n * 256 + ((((kk >> 3) ^ (n & 7)) << 3) | (kk & 7))] = (short)f2bf(nW1[kk * 64 + n]);
    }
    for (int i = tid; i < 4096; i += 256) {
        int n = i >> 6, kk = i & 63;
        W2t[n * 64 + ((((kk >> 3) ^ (n & 7)) << 3) | (kk & 7))] = (short)f2bf(nW2[kk * 64 + n]);
    }
    if (tid < 64) {
        pb[tid]       = nb1[tid];
        pb[64 + tid]  = ng1[tid];
        pb[128 + tid] = nbt1[tid];
        pb[192 + tid] = nb2[tid];
        pb[256 + tid] = ng2[tid];
        pb[320 + tid] = nbt2[tid];
    }
    __syncthreads();   // only barrier
    const int wave = tid >> 6, lane = tid & 63, l15 = lane & 15, g = lane >> 4;
    const int x7 = l15 & 7;
    const int unit = blockIdx.x * 4 + wave;          // 1024 units
    const int br = unit >> 9;
    const int nb_ = (unit & 511) * 16;
    const float* h = br ? hB : hA;
    const float* orig = br ? origB : origA;
    const float* aggr = br ? aggrB : aggrA;
    const size_t outbase = br ? 573440 : 24576;

    const int row = nb_ + l15;

    bf16x8 af[8];
    af[0] = cvt8v(h + (size_t)row * 64 + 8 * g);
    af[1] = cvt8v(h + (size_t)row * 64 + 32 + 8 * g);
    af[2] = cvt8v(aggr + (size_t)row * 64 + 8 * g);
    af[3] = cvt8v(aggr + (size_t)row * 64 + 32 + 8 * g);
    if (br == 0) {
        af[4] = *(const bf16x8*)(attb + (size_t)row * 64 + 8 * g);
        af[5] = *(const bf16x8*)(attb + (size_t)row * 64 + 32 + 8 * g);
    } else {
        af[4] = (bf16x8)0;
        af[5] = (bf16x8)0;
    }
    af[6] = cvt8v(orig + (size_t)row * 64 + 8 * g);
    af[7] = cvt8v(orig + (size_t)row * 64 + 32 + 8 * g);

    floatx4 acc1[4];
    #pragma unroll
    for (int t = 0; t < 4; t++) acc1[t] = (floatx4)0.0f;
    #pragma unroll
    for (int c = 0; c < 8; c++) {
        #pragma unroll
        for (int t = 0; t < 4; t++) {
            bf16x8 b = *(const bf16x8*)(&W1t[(t * 16 + l15) * 256 + ((((c << 2) | g) ^ x7) << 3)]);
            acc1[t] = MFMA16(af[c], b, acc1[t]);
        }
    }
    float vv[4][4];
    #pragma unroll
    for (int t = 0; t < 4; t++)
        #pragma unroll
        for (int r = 0; r < 4; r++) vv[t][r] = acc1[t][r] + pb[t * 16 + l15];
    #pragma unroll
    for (int r = 0; r < 4; r++) {
        float s1 = vv[0][r] + vv[1][r] + vv[2][r] + vv[3][r];
        float s2 = vv[0][r] * vv[0][r] + vv[1][r] * vv[1][r] + vv[2][r] * vv[2][r] + vv[3][r] * vv[3][r];
        s1 = rowsum16(s1);
        s2 = rowsum16(s2);
        float mean = s1 * 0.015625f;
        float rstd = ln_rstd(s2, mean);
        int rw = 4 * g + r;
        int rbase = rw * 64;
        int r7 = rw & 7;
        #pragma unroll
        for (int t = 0; t < 4; t++) {
            int colx = t * 16 + l15;
            float x = (vv[t][r] - mean) * rstd * pb[64 + colx] + pb[128 + colx];
            x = lrelu(x);
            ubuf[wave][rbase + (((((t << 1) | (l15 >> 3)) ^ r7) << 3) | x7)] = (short)f2bf(x);
        }
    }
    bf16x8 a2[2];
    a2[0] = *(const bf16x8*)(&ubuf[wave][l15 * 64 + (((g) ^ x7) << 3)]);
    a2[1] = *(const bf16x8*)(&ubuf[wave][l15 * 64 + (((4 | g) ^ x7) << 3)]);
    floatx4 acc2[4];
    #pragma unroll
    for (int t = 0; t < 4; t++) acc2[t] = (floatx4)0.0f;
    #pragma unroll
    for (int c = 0; c < 2; c++) {
        #pragma unroll
        for (int t = 0; t < 4; t++) {
            bf16x8 b = *(const bf16x8*)(&W2t[(t * 16 + l15) * 64 + ((((c << 2) | g) ^ x7) << 3)]);
            acc2[t] = MFMA16(a2[c], b, acc2[t]);
        }
    }
    float u2[4][4];
    #pragma unroll
    for (int t = 0; t < 4; t++)
        #pragma unroll
        for (int r = 0; r < 4; r++) u2[t][r] = acc2[t][r] + pb[192 + t * 16 + l15];
    #pragma unroll
    for (int r = 0; r < 4; r++) {
        float s1 = u2[0][r] + u2[1][r] + u2[2][r] + u2[3][r];
        float s2 = u2[0][r] * u2[0][r] + u2[1][r] * u2[1][r] + u2[2][r] * u2[2][r] + u2[3][r] * u2[3][r];
        s1 = rowsum16(s1);
        s2 = rowsum16(s2);
        float mean = s1 * 0.015625f;
        float rstd = ln_rstd(s2, mean);
        #pragma unroll
        for (int t = 0; t < 4; t++) {
            int colx = t * 16 + l15;
            float u = (u2[t][r] - mean) * rstd * pb[256 + colx] + pb[320 + colx];
            size_t orow = (size_t)(nb_ + 4 * g + r);
            float hh = h[orow * 64 + colx];
            out[outbase + orow * 64 + colx] = 0.5f * u + 0.5f * hh;
        }
    }
}

// ---------------------------------------------------------------------------
__global__ void xnew_kernel(
    const float* __restrict__ coordsA, const float* __restrict__ origcA,
    const float* __restrict__ coordsB, const float* __restrict__ origcB,
    const float* __restrict__ xupA, const float* __restrict__ xupB,
    const int* __restrict__ rowptrA, const int* __restrict__ rowptrB,
    float* __restrict__ out)
{
    int i = blockIdx.x * 256 + threadIdx.x;   // 49152 total
    int br = (i >= 24576) ? 1 : 0;
    int j = i - br * 24576;
    const float* coords = br ? coordsB : coordsA;
    const float* origc = br ? origcB : origcA;
    const float* xup = br ? xupB : xupA;
    const int* rp = br ? rowptrB : rowptrA;
    int node = j / 3;
    float cnt = (float)(rp[node + 1] - rp[node]);
    float val = 0.25f * origc[j] + 0.75f * coords[j] + xup[j] / fmaxf(cnt, 1.0f);
    out[(br ? 548864 : 0) + j] = val;
}

// ---------------------------------------------------------------------------
extern "C" void kernel_launch(void* const* d_in, const int* in_sizes, int n_in,
                              void* d_out, int out_size, void* d_ws, size_t ws_size,
                              hipStream_t stream)
{
    int base = n_in - 29;
    for (int i = 0; i < n_in; i++) {
        if (in_sizes[i] == 11200) { base = i; break; }
    }
    const float* coordsA = (const float*)d_in[0];
    const float* hA      = (const float*)d_in[1];
    const float* origA   = (const float*)d_in[2];
    const float* origcA  = (const float*)d_in[3];
    const float* efA     = (const float*)d_in[4];
    const float* coordsB = (const float*)d_in[5];
    const float* hB      = (const float*)d_in[6];
    const float* origB   = (const float*)d_in[7];
    const float* origcB  = (const float*)d_in[8];
    const float* efB     = (const float*)d_in[9];
    const float* P[25];
    for (int k = 0; k < 25; k++) P[k] = (const float*)d_in[base + k];
    const int* srcA = (const int*)d_in[base + 25];
    const int* dstA = (const int*)d_in[base + 26];
    const int* srcB = (const int*)d_in[base + 27];
    const int* dstB = (const int*)d_in[base + 28];

    char* ws = (char*)d_ws;
    unsigned short* msgbufA = (unsigned short*)(ws + 0);          // 33.5 MB
    unsigned short* msgbufB = (unsigned short*)(ws + 33554432);   // 33.5 MB
    float* Opart  = (float*)(ws + 0);                             // 16 MB (reuse after gather)
    float* mlbuf  = (float*)(ws + 16777216);                      // 512 KB (reuse)
    unsigned short* hbA  = (unsigned short*)(ws + 67108864);      // 1 MB
    unsigned short* hbB  = (unsigned short*)(ws + 68157440);
    unsigned short* efbA = (unsigned short*)(ws + 69206016);      // 16 MB
    unsigned short* efbB = (unsigned short*)(ws + 85983232);
    float* aggrA  = (float*)(ws + 102760448);                     // 2 MB
    float* aggrB  = (float*)(ws + 104857600);
    unsigned short* qbuf = (unsigned short*)(ws + 106954752);     // 1 MB
    unsigned short* kbuf = (unsigned short*)(ws + 108003328);
    unsigned short* vTb  = (unsigned short*)(ws + 109051904);
    unsigned short* attb = (unsigned short*)(ws + 110100480);
    // zero region (one memset, 327,680 B): xupA,xupB,histA,histB,curA,curB
    float* xupA = (float*)(ws + 111149056);
    float* xupB = (float*)(ws + 111247360);
    int* histA  = (int*)(ws + 111345664);
    int* histB  = (int*)(ws + 111378432);
    int* curA   = (int*)(ws + 111411200);
    int* curB   = (int*)(ws + 111443968);
    int* rowptrA = (int*)(ws + 111476736);
    int* rowptrB = (int*)(ws + 111517696);
    int* posA   = (int*)(ws + 111558656);                          // 1 MB
    int* posB   = (int*)(ws + 112607232);                          // 1 MB
    float* out = (float*)d_out;

    hipMemsetAsync(ws + 111149056, 0, 327680, stream);

    prep_kernel<<<17408, 256, 0, stream>>>(hA, hB, efA, efB, hbA, hbB, efbA, efbB);

    hist_kernel<<<1024, 256, 0, stream>>>(dstA, dstB, histA, histB);
    scan_kernel<<<2, 1024, 0, stream>>>(histA, histB, rowptrA, rowptrB);
    scatter_kernel<<<1024, 256, 0, stream>>>(dstA, dstB, rowptrA, rowptrB,
                                             curA, curB, posA, posB);

    edge_kernel<<<1024, 512, 0, stream>>>(
        coordsA, hbA, efbA, srcA, dstA, posA,
        coordsB, hbB, efbB, srcB, dstB, posB,
        P[0], P[1], P[2], P[3], P[4], P[5], P[6], P[7],
        P[19], P[20], P[21], P[22], P[23], P[24],
        msgbufA, msgbufB, xupA, xupB);

    gather_kernel<<<2048, 256, 0, stream>>>(rowptrA, rowptrB, msgbufA, msgbufB,
                                            aggrA, aggrB);

    qkv_kernel<<<128, 256, 0, stream>>>(hbA, hbB, P[8], P[9], P[10], qbuf, kbuf, vTb);

    attn_kernel<<<1024, 256, 0, stream>>>(qbuf, kbuf, vTb, Opart, mlbuf);
    combine_kernel<<<2048, 256, 0, stream>>>(Opart, mlbuf, attb);

    node_kernel<<<256, 256, 0, stream>>>(
        hA, hB, origA, origB, attb, aggrA, aggrB,
        P[11], P[12], P[13], P[14], P[15], P[16], P[17], P[18], out);

    xnew_kernel<<<192, 256, 0, stream>>>(
        coordsA, origcA, coordsB, origcB, xupA, xupB, rowptrA, rowptrB, out);
}